// Round 7
// baseline (201.595 us; speedup 1.0000x reference)
//
#include <hip/hip_runtime.h>
#include <cstdint>
#include <cstddef>

#define BB 16
#define CC 256
#define NP 1024   // H*W

typedef __attribute__((ext_vector_type(8))) short bf16x8;
typedef __attribute__((ext_vector_type(4))) float f32x4;
typedef unsigned short u16;

__device__ __forceinline__ u16 f2bf(float f) {
    union { float f; uint32_t u; } v; v.f = f;
    uint32_t u = v.u;
    return (u16)((u + 0x7FFFu + ((u >> 16) & 1u)) >> 16);   // RNE
}

// ---------------- SE mean (blocks 0..4095) + weight convert (blocks 4096..4607) ----------------
__global__ __launch_bounds__(256)
void se_mean_conv_kernel(const float* __restrict__ x, float* __restrict__ s_mean,
                         const float* __restrict__ w1, u16* __restrict__ d1,
                         const float* __restrict__ w2, u16* __restrict__ d2) {
    int blk = blockIdx.x;
    int t = threadIdx.x;
    if (blk < BB * CC) {
        const float* p = x + (size_t)blk * NP;
        float4 v = *(const float4*)(p + t * 4);
        float s = (v.x + v.y) + (v.z + v.w);
#pragma unroll
        for (int off = 32; off; off >>= 1) s += __shfl_down(s, off, 64);
        __shared__ float red[4];
        if ((t & 63) == 0) red[t >> 6] = s;
        __syncthreads();
        if (t == 0) s_mean[blk] = (red[0] + red[1] + red[2] + red[3]) * (1.0f / NP);
    } else {
        int blk2 = blk - BB * CC;
        const float* src = (blk2 < 256) ? w1 : w2;
        u16* dst = (blk2 < 256) ? d1 : d2;
        int i = ((blk2 & 255) * 256 + t) * 4;
        float4 v = *(const float4*)(src + i);
        ushort4 o;
        o.x = f2bf(v.x); o.y = f2bf(v.y); o.z = f2bf(v.z); o.w = f2bf(v.w);
        *(ushort4*)(dst + i) = o;
    }
}

// ---- scale + transpose + per-block SE-mlp (+ fused qkv on ct==0 blocks) ----
__global__ __launch_bounds__(256)
void scale_transpose_qkv_kernel(const float* __restrict__ x, const float* __restrict__ s_mean,
                                const float* __restrict__ fc1_w, const float* __restrict__ fc1_b,
                                const float* __restrict__ fc2_w, const float* __restrict__ fc2_b,
                                const float* __restrict__ qW, const float* __restrict__ qB,
                                u16* __restrict__ ygt, u16* __restrict__ Qt,
                                u16* __restrict__ Kt, u16* __restrict__ Vb) {
    // grid: (16 nt, 4 ct, BB)
    int nt = blockIdx.x, ct = blockIdx.y, b = blockIdx.z;
    __shared__ float tile[64][65];
    __shared__ float ws[64 * 32];
    __shared__ float bs[64];
    __shared__ float vtile[32][64];
    __shared__ float smean_s[CC];
    __shared__ float h1[64];
    __shared__ float sig_l[64];
    int t = threadIdx.x;
    const float* Xb = x + ((size_t)b * CC + ct * 64) * NP + nt * 64;
    smean_s[t] = s_mean[b * CC + t];
    if (ct == 0) {
        for (int e = t; e < 2048; e += 256) ws[e] = qW[e];
        if (t < 64) bs[t] = qB[t];
    }
#pragma unroll
    for (int p = 0; p < 4; ++p) {
        int e = t + p * 256;
        int c = e >> 4, n4 = (e & 15) * 4;
        float4 v = *(const float4*)&Xb[(size_t)c * NP + n4];
        tile[c][n4] = v.x; tile[c][n4 + 1] = v.y; tile[c][n4 + 2] = v.z; tile[c][n4 + 3] = v.w;
    }
    __syncthreads();
    if (t < 64) {
        float a = fc1_b[t];
#pragma unroll 4
        for (int c = 0; c < CC; ++c) a += fc1_w[t * CC + c] * smean_s[c];
        h1[t] = fmaxf(a, 0.f);
    }
    __syncthreads();
    if (t < 64) {
        int c = ct * 64 + t;
        float a = fc2_b[c];
#pragma unroll 8
        for (int j = 0; j < 64; ++j) a += fc2_w[c * 64 + j] * h1[j];
        sig_l[t] = 1.f / (1.f + __expf(-a));
    }
    __syncthreads();
    u16* Yb = ygt + ((size_t)b * NP + nt * 64) * CC + ct * 64;
#pragma unroll
    for (int p = 0; p < 4; ++p) {
        int e = t + p * 256;
        int n = e >> 4, c4 = (e & 15) * 4;
        if (ct * 64 + c4 >= 32) {
            ushort4 o;
            o.x = f2bf(tile[c4][n] * sig_l[c4]);
            o.y = f2bf(tile[c4 + 1][n] * sig_l[c4 + 1]);
            o.z = f2bf(tile[c4 + 2][n] * sig_l[c4 + 2]);
            o.w = f2bf(tile[c4 + 3][n] * sig_l[c4 + 3]);
            *(ushort4*)&Yb[(size_t)n * CC + c4] = o;
        }
    }
    if (ct == 0) {
        int nn = t & 63, g = t >> 6;
        int n = nt * 64 + nn;
        float xs[32];
#pragma unroll
        for (int c = 0; c < 32; ++c) xs[c] = tile[c][nn] * sig_l[c];
        float acc[16];
#pragma unroll
        for (int oc = 0; oc < 16; ++oc) {
            int o = g * 16 + oc;
            float a = bs[o];
#pragma unroll
            for (int c = 0; c < 32; ++c) a += ws[o * 32 + c] * xs[c];
            acc[oc] = a;
        }
        if (g == 0) {
            u16* qr = Qt + ((size_t)b * NP + n) * 32;
            ushort4 z4; z4.x = 0; z4.y = 0; z4.z = 0; z4.w = 0;
#pragma unroll
            for (int j = 0; j < 16; j += 4) {
                ushort4 o4;
                o4.x = f2bf(acc[j] * 0.25f);     o4.y = f2bf(acc[j + 1] * 0.25f);
                o4.z = f2bf(acc[j + 2] * 0.25f); o4.w = f2bf(acc[j + 3] * 0.25f);
                *(ushort4*)&qr[j] = o4;
            }
            *(ushort4*)&qr[16] = z4; *(ushort4*)&qr[20] = z4;
            *(ushort4*)&qr[24] = z4; *(ushort4*)&qr[28] = z4;
        } else if (g == 1) {
            u16* kr = Kt + ((size_t)b * NP + n) * 32;
            ushort4 z4; z4.x = 0; z4.y = 0; z4.z = 0; z4.w = 0;
#pragma unroll
            for (int j = 0; j < 16; j += 4) {
                ushort4 k4;
                k4.x = f2bf(acc[j]);     k4.y = f2bf(acc[j + 1]);
                k4.z = f2bf(acc[j + 2]); k4.w = f2bf(acc[j + 3]);
                *(ushort4*)&kr[j] = k4;
            }
            *(ushort4*)&kr[16] = z4; *(ushort4*)&kr[20] = z4;
            *(ushort4*)&kr[24] = z4; *(ushort4*)&kr[28] = z4;
        } else {
#pragma unroll
            for (int oc = 0; oc < 16; ++oc) vtile[(g - 2) * 16 + oc][nn] = acc[oc];
        }
        __syncthreads();
        for (int e = t; e < 2048; e += 256) {
            int c = e >> 6, nn2 = e & 63;
            Vb[(size_t)b * 32 * NP + (size_t)c * NP + nt * 64 + nn2] = f2bf(vtile[c][nn2]);
        }
    }
}

// ---------------- MFMA flash attention + fused proj (unchanged from R6) ----------------
__global__ __launch_bounds__(256)
void attn_mfma_kernel(const u16* __restrict__ Qt, const u16* __restrict__ Kt,
                      const u16* __restrict__ Vb,
                      const float* __restrict__ proj_w, const float* __restrict__ proj_b,
                      u16* __restrict__ ygt) {
    int b = blockIdx.x >> 6;
    int n0 = (blockIdx.x & 63) * 16;
    __shared__ __align__(16) u16 P_lds[4][16][40];
    __shared__ float al_lds[4][16];
    __shared__ float sm_lds[4][16];
    __shared__ float sl_lds[4][16];
    __shared__ float O_lds[4][16][33];
    __shared__ float pw_s[32][32];
    __shared__ float pb_s[32];
    int t = threadIdx.x;
    int w = t >> 6, lane = t & 63;
    int q = lane >> 4, idx = lane & 15;

    for (int e = t; e < 1024; e += 256) pw_s[e >> 5][e & 31] = proj_w[e];
    if (t < 32) pb_s[t] = proj_b[t];
    __syncthreads();

    const u16* Qb = Qt + (size_t)b * NP * 32;
    const u16* Kb = Kt + (size_t)b * NP * 32;
    const u16* Vp = Vb + (size_t)b * 32 * NP;

    int nrow = n0 + idx;
    bf16x8 aq = *(const bf16x8*)&Qb[(size_t)nrow * 32 + q * 8];

    f32x4 O0 = {0.f, 0.f, 0.f, 0.f}, O1 = {0.f, 0.f, 0.f, 0.f};
    float m_run[4] = {-1e30f, -1e30f, -1e30f, -1e30f};
    float l_run[4] = {0.f, 0.f, 0.f, 0.f};

    int mbase = w * 256;
    for (int m0 = mbase; m0 < mbase + 256; m0 += 32) {
        bf16x8 bk0 = *(const bf16x8*)&Kb[(size_t)(m0 + idx) * 32 + q * 8];
        bf16x8 bk1 = *(const bf16x8*)&Kb[(size_t)(m0 + 16 + idx) * 32 + q * 8];
        bf16x8 va0 = *(const bf16x8*)&Vp[(size_t)idx * NP + m0 + q * 8];
        bf16x8 va1 = *(const bf16x8*)&Vp[(size_t)(16 + idx) * NP + m0 + q * 8];
        f32x4 z = {0.f, 0.f, 0.f, 0.f};
        f32x4 S0 = __builtin_amdgcn_mfma_f32_16x16x32_bf16(aq, bk0, z, 0, 0, 0);
        f32x4 S1 = __builtin_amdgcn_mfma_f32_16x16x32_bf16(aq, bk1, z, 0, 0, 0);
        float mx[4], p0[4], p1[4], alpha[4];
#pragma unroll
        for (int r = 0; r < 4; ++r) mx[r] = fmaxf(S0[r], S1[r]);
#pragma unroll
        for (int off = 1; off < 16; off <<= 1)
#pragma unroll
            for (int r = 0; r < 4; ++r) mx[r] = fmaxf(mx[r], __shfl_xor(mx[r], off, 64));
#pragma unroll
        for (int r = 0; r < 4; ++r) {
            float nm = fmaxf(m_run[r], mx[r]);
            alpha[r] = __expf(m_run[r] - nm);
            m_run[r] = nm;
            p0[r] = __expf(S0[r] - nm);
            p1[r] = __expf(S1[r] - nm);
        }
#pragma unroll
        for (int r = 0; r < 4; ++r) {
            float s = p0[r] + p1[r];
#pragma unroll
            for (int off = 1; off < 16; off <<= 1) s += __shfl_xor(s, off, 64);
            l_run[r] = l_run[r] * alpha[r] + s;
        }
#pragma unroll
        for (int r = 0; r < 4; ++r) {
            P_lds[w][q * 4 + r][idx]      = f2bf(p0[r]);
            P_lds[w][q * 4 + r][idx + 16] = f2bf(p1[r]);
        }
        if (idx == 0) {
#pragma unroll
            for (int r = 0; r < 4; ++r) al_lds[w][q * 4 + r] = alpha[r];
        }
        float an = al_lds[w][idx];
#pragma unroll
        for (int r = 0; r < 4; ++r) { O0[r] *= an; O1[r] *= an; }
        bf16x8 pf = *(const bf16x8*)&P_lds[w][idx][q * 8];
        O0 = __builtin_amdgcn_mfma_f32_16x16x32_bf16(va0, pf, O0, 0, 0, 0);
        O1 = __builtin_amdgcn_mfma_f32_16x16x32_bf16(va1, pf, O1, 0, 0, 0);
    }
    if (idx == 0) {
#pragma unroll
        for (int r = 0; r < 4; ++r) {
            sm_lds[w][q * 4 + r] = m_run[r];
            sl_lds[w][q * 4 + r] = l_run[r];
        }
    }
#pragma unroll
    for (int r = 0; r < 4; ++r) {
        O_lds[w][idx][q * 4 + r]      = O0[r];
        O_lds[w][idx][q * 4 + r + 16] = O1[r];
    }
    __syncthreads();
    if (w == 0) {
        float m0_ = sm_lds[0][idx], m1 = sm_lds[1][idx], m2 = sm_lds[2][idx], m3 = sm_lds[3][idx];
        float gm = fmaxf(fmaxf(m0_, m1), fmaxf(m2, m3));
        float e0 = __expf(m0_ - gm), e1 = __expf(m1 - gm);
        float e2 = __expf(m2 - gm), e3 = __expf(m3 - gm);
        float linv = 1.f / (sl_lds[0][idx] * e0 + sl_lds[1][idx] * e1 +
                            sl_lds[2][idx] * e2 + sl_lds[3][idx] * e3);
#pragma unroll
        for (int r = 0; r < 4; ++r) {
            int c0 = q * 4 + r;
            O_lds[0][idx][c0] = (O_lds[0][idx][c0] * e0 + O_lds[1][idx][c0] * e1 +
                                 O_lds[2][idx][c0] * e2 + O_lds[3][idx][c0] * e3) * linv;
            int c1 = c0 + 16;
            O_lds[0][idx][c1] = (O_lds[0][idx][c1] * e0 + O_lds[1][idx][c1] * e1 +
                                 O_lds[2][idx][c1] * e2 + O_lds[3][idx][c1] * e3) * linv;
        }
        float o0[4], o1[4];
#pragma unroll
        for (int r = 0; r < 4; ++r) { o0[r] = pb_s[q * 4 + r]; o1[r] = pb_s[q * 4 + r + 16]; }
#pragma unroll
        for (int c = 0; c < 32; ++c) {
            float xv = O_lds[0][idx][c];
#pragma unroll
            for (int r = 0; r < 4; ++r) {
                o0[r] += pw_s[q * 4 + r][c] * xv;
                o1[r] += pw_s[q * 4 + r + 16][c] * xv;
            }
        }
        u16* yrow = ygt + ((size_t)b * NP + n0 + idx) * CC;
        ushort4 w0, w1;
        w0.x = f2bf(o0[0]); w0.y = f2bf(o0[1]); w0.z = f2bf(o0[2]); w0.w = f2bf(o0[3]);
        w1.x = f2bf(o1[0]); w1.y = f2bf(o1[1]); w1.z = f2bf(o1[2]); w1.w = f2bf(o1[3]);
        *(ushort4*)&yrow[q * 4] = w0;
        *(ushort4*)&yrow[q * 4 + 16] = w1;
    }
}

// ---------------- Fused FFN: out = W2 @ relu(W1 @ y) , no ht round-trip ----------------
// 256 blocks, 64-pixel n-tile each; wave w owns n-cols w*16..+16 (h is wave-private).
// LDS 80 KB -> 2 blocks/CU. W strips streamed dbuf via global_load_lds, 16B-chunk
// XOR swizzle (chunk ^ row&7) keeps both the staging contiguous and ds_read_b128 2-way.
#define STAGE_W1(R0, DST)                                                                   \
    {                                                                                       \
        _Pragma("unroll")                                                                   \
        for (int is_ = 0; is_ < 4; ++is_) {                                                 \
            int seg_ = is_ * 4 + w;                                                         \
            int chunk_ = seg_ * 64 + lane;                                                  \
            int row_ = chunk_ >> 5, c_ = chunk_ & 31;                                       \
            __builtin_amdgcn_global_load_lds(                                               \
                (const __attribute__((address_space(1))) void*)(w1 + (((size_t)((R0) + row_)) << 8) + ((c_ ^ (row_ & 7)) << 3)), \
                (__attribute__((address_space(3))) void*)((DST) + seg_ * 512),              \
                16, 0, 0);                                                                  \
        }                                                                                   \
    }
#define STAGE_W2(C0, KOFF, DST)                                                             \
    {                                                                                       \
        _Pragma("unroll")                                                                   \
        for (int is_ = 0; is_ < 2; ++is_) {                                                 \
            int seg_ = is_ * 4 + w;                                                         \
            int chunk_ = seg_ * 64 + lane;                                                  \
            int row_ = chunk_ >> 4, c_ = chunk_ & 15;                                       \
            __builtin_amdgcn_global_load_lds(                                               \
                (const __attribute__((address_space(1))) void*)(w2 + (((size_t)((C0) + row_)) << 10) + (KOFF) + ((c_ ^ (row_ & 7)) << 3)), \
                (__attribute__((address_space(3))) void*)((DST) + seg_ * 512),              \
                16, 0, 0);                                                                  \
        }                                                                                   \
    }

__global__ __launch_bounds__(256)
void ffn_fused_kernel(const u16* __restrict__ ygt,   // [16384][256] bf16
                      const u16* __restrict__ w1,    // [1024][256] bf16
                      const float* __restrict__ b1,  // [1024]
                      const u16* __restrict__ w2,    // [256][1024] bf16
                      const float* __restrict__ b2,  // [256]
                      float* __restrict__ out) {     // [16][256][1024] fp32
    __shared__ __align__(16) u16 y_lds[64 * 256];    // 32 KB
    __shared__ __align__(16) u16 h_lds[64 * 128];    // 16 KB (wave-private rows)
    __shared__ __align__(16) u16 wst[2][8192];       // 2 x 16 KB
    int nt = blockIdx.x;
    int t = threadIdx.x;
    int w = t >> 6, lane = t & 63;
    int q = lane >> 4, idx = lane & 15;
    int sw = idx & 7;

    // stage y-tile: 64 rows x 512B contiguous, swizzled
    const u16* ysrc = ygt + (size_t)nt * 64 * 256;
#pragma unroll
    for (int is = 0; is < 8; ++is) {
        int seg = is * 4 + w;
        int chunk = seg * 64 + lane;
        int row = chunk >> 5, c = chunk & 31;
        __builtin_amdgcn_global_load_lds(
            (const __attribute__((address_space(1))) void*)(ysrc + ((size_t)row << 8) + ((c ^ (row & 7)) << 3)),
            (__attribute__((address_space(3))) void*)(y_lds + seg * 512),
            16, 0, 0);
    }
    STAGE_W1(0, &wst[0][0])
    __syncthreads();

    f32x4 acc[16];
#pragma unroll
    for (int i = 0; i < 16; ++i) { f32x4 z = {0.f, 0.f, 0.f, 0.f}; acc[i] = z; }

    int buf = 0;
    for (int hc = 0; hc < 8; ++hc) {
        // ---- FFN1: h[128 k2][my 16 n] = relu(W1[hc*128..][256] @ y) ----
        for (int s = 0; s < 4; ++s) {
            if (s < 3) STAGE_W1(hc * 128 + (s + 1) * 32, &wst[buf ^ 1][0])
            else       STAGE_W2(0, (size_t)hc * 128, &wst[buf ^ 1][0])
#pragma unroll
            for (int ti = 0; ti < 2; ++ti) {
                f32x4 a2 = {0.f, 0.f, 0.f, 0.f};
#pragma unroll
                for (int kwin = 0; kwin < 8; ++kwin) {
                    int ga = kwin * 4 + q;
                    bf16x8 af = *(const bf16x8*)&wst[buf][((ti * 16 + idx) * 32 + (ga ^ sw)) * 8];
                    bf16x8 bfr = *(const bf16x8*)&y_lds[((w * 16 + idx) * 32 + (ga ^ sw)) * 8];
                    a2 = __builtin_amdgcn_mfma_f32_16x16x32_bf16(af, bfr, a2, 0, 0, 0);
                }
                int k2g = hc * 128 + s * 32 + ti * 16 + q * 4;
                float4 bb = *(const float4*)&b1[k2g];
                float r0 = fmaxf(a2[0] + bb.x, 0.f), r1 = fmaxf(a2[1] + bb.y, 0.f);
                float r2 = fmaxf(a2[2] + bb.z, 0.f), r3 = fmaxf(a2[3] + bb.w, 0.f);
                ushort4 o;
                o.x = f2bf(r0); o.y = f2bf(r1); o.z = f2bf(r2); o.w = f2bf(r3);
                int g = s * 4 + ti * 2 + (q >> 1);
                *(ushort4*)&h_lds[(w * 16 + idx) * 128 + (g ^ sw) * 8 + (q & 1) * 4] = o;
            }
            __syncthreads();
            buf ^= 1;
        }
        // ---- FFN2 partial: acc += W2[:, hc*128..+128] @ h ----
        for (int s2 = 0; s2 < 8; ++s2) {
            if (s2 < 7)      STAGE_W2((s2 + 1) * 32, (size_t)hc * 128, &wst[buf ^ 1][0])
            else if (hc < 7) STAGE_W1((hc + 1) * 128, &wst[buf ^ 1][0])
#pragma unroll
            for (int ti = 0; ti < 2; ++ti) {
                int ct = s2 * 2 + ti;
#pragma unroll
                for (int kwin = 0; kwin < 4; ++kwin) {
                    int ga = kwin * 4 + q;
                    bf16x8 af = *(const bf16x8*)&wst[buf][((ti * 16 + idx) * 16 + (ga ^ sw)) * 8];
                    bf16x8 bfr = *(const bf16x8*)&h_lds[((w * 16 + idx) * 16 + (ga ^ sw)) * 8];
                    acc[ct] = __builtin_amdgcn_mfma_f32_16x16x32_bf16(af, bfr, acc[ct], 0, 0, 0);
                }
            }
            __syncthreads();
            buf ^= 1;
        }
    }

    // epilogue: out[b][c][n] fp32, coalesced along n
    int nfl = nt * 64 + w * 16 + idx;
    int bo = nfl >> 10, npix = nfl & 1023;
#pragma unroll
    for (int ct = 0; ct < 16; ++ct) {
        int c0 = ct * 16 + q * 4;
        float4 bb = *(const float4*)&b2[c0];
        float* p = out + ((size_t)bo * 256 + c0) * 1024 + npix;
        p[0]        = acc[ct][0] + bb.x;
        p[1024]     = acc[ct][1] + bb.y;
        p[2 * 1024] = acc[ct][2] + bb.z;
        p[3 * 1024] = acc[ct][3] + bb.w;
    }
}

extern "C" void kernel_launch(void* const* d_in, const int* in_sizes, int n_in,
                              void* d_out, int out_size, void* d_ws, size_t ws_size,
                              hipStream_t stream) {
    const float* x      = (const float*)d_in[0];
    const float* fc1_w  = (const float*)d_in[1];
    const float* fc1_b  = (const float*)d_in[2];
    const float* fc2_w  = (const float*)d_in[3];
    const float* fc2_b  = (const float*)d_in[4];
    const float* qkv_w  = (const float*)d_in[5];
    const float* qkv_b  = (const float*)d_in[6];
    const float* proj_w = (const float*)d_in[7];
    const float* proj_b = (const float*)d_in[8];
    const float* ffn1_w = (const float*)d_in[9];
    const float* ffn1_b = (const float*)d_in[10];
    const float* ffn2_w = (const float*)d_in[11];
    const float* ffn2_b = (const float*)d_in[12];
    float* out = (float*)d_out;

    u16* w1b = (u16*)d_ws;                           // 512 KB
    u16* w2b = w1b + 262144;                         // 512 KB
    u16* ygt = w2b + 262144;                         // [16384][256] bf16, 8 MB
    float* s_mean = (float*)(ygt + (size_t)BB * NP * CC);  // 16 KB
    u16* Qt = (u16*)(s_mean + BB * CC);              // 1 MB
    u16* Kt = Qt + (size_t)BB * NP * 32;             // 1 MB
    u16* Vb = Kt + (size_t)BB * NP * 32;             // 1 MB

    se_mean_conv_kernel<<<BB * CC + 512, 256, 0, stream>>>(x, s_mean, ffn1_w, w1b, ffn2_w, w2b);
    scale_transpose_qkv_kernel<<<dim3(16, 4, BB), 256, 0, stream>>>(
        x, s_mean, fc1_w, fc1_b, fc2_w, fc2_b, qkv_w, qkv_b, ygt, Qt, Kt, Vb);
    attn_mfma_kernel<<<BB * 64, 256, 0, stream>>>(Qt, Kt, Vb, proj_w, proj_b, ygt);
    ffn_fused_kernel<<<256, 256, 0, stream>>>(ygt, w1b, ffn1_b, w2b, ffn2_b, out);
}

// Round 8
// 182.398 us; speedup vs baseline: 1.1052x; 1.1052x over previous
//
#include <hip/hip_runtime.h>
#include <cstdint>
#include <cstddef>

#define BB 16
#define CC 256
#define NP 1024   // H*W

typedef __attribute__((ext_vector_type(8))) short bf16x8;
typedef __attribute__((ext_vector_type(4))) float f32x4;
typedef unsigned short u16;

__device__ __forceinline__ u16 f2bf(float f) {
    union { float f; uint32_t u; } v; v.f = f;
    uint32_t u = v.u;
    return (u16)((u + 0x7FFFu + ((u >> 16) & 1u)) >> 16);   // RNE
}

// ---------------- SE mean (blocks 0..4095) + weight convert (blocks 4096..4607) ----------------
__global__ __launch_bounds__(256)
void se_mean_conv_kernel(const float* __restrict__ x, float* __restrict__ s_mean,
                         const float* __restrict__ w1, u16* __restrict__ d1,
                         const float* __restrict__ w2, u16* __restrict__ d2) {
    int blk = blockIdx.x;
    int t = threadIdx.x;
    if (blk < BB * CC) {
        const float* p = x + (size_t)blk * NP;
        float4 v = *(const float4*)(p + t * 4);
        float s = (v.x + v.y) + (v.z + v.w);
#pragma unroll
        for (int off = 32; off; off >>= 1) s += __shfl_down(s, off, 64);
        __shared__ float red[4];
        if ((t & 63) == 0) red[t >> 6] = s;
        __syncthreads();
        if (t == 0) s_mean[blk] = (red[0] + red[1] + red[2] + red[3]) * (1.0f / NP);
    } else {
        int blk2 = blk - BB * CC;
        const float* src = (blk2 < 256) ? w1 : w2;
        u16* dst = (blk2 < 256) ? d1 : d2;
        int i = ((blk2 & 255) * 256 + t) * 4;
        float4 v = *(const float4*)(src + i);
        ushort4 o;
        o.x = f2bf(v.x); o.y = f2bf(v.y); o.z = f2bf(v.z); o.w = f2bf(v.w);
        *(ushort4*)(dst + i) = o;
    }
}

// ---- scale + transpose + per-block SE-mlp (+ fused qkv on ct==0 blocks) ----
__global__ __launch_bounds__(256)
void scale_transpose_qkv_kernel(const float* __restrict__ x, const float* __restrict__ s_mean,
                                const float* __restrict__ fc1_w, const float* __restrict__ fc1_b,
                                const float* __restrict__ fc2_w, const float* __restrict__ fc2_b,
                                const float* __restrict__ qW, const float* __restrict__ qB,
                                u16* __restrict__ ygt, u16* __restrict__ Qt,
                                u16* __restrict__ Kt, u16* __restrict__ Vb) {
    // grid: (16 nt, 4 ct, BB)
    int nt = blockIdx.x, ct = blockIdx.y, b = blockIdx.z;
    __shared__ float tile[64][65];
    __shared__ float ws[64 * 32];
    __shared__ float bs[64];
    __shared__ float vtile[32][64];
    __shared__ float smean_s[CC];
    __shared__ float h1[64];
    __shared__ float sig_l[64];
    int t = threadIdx.x;
    const float* Xb = x + ((size_t)b * CC + ct * 64) * NP + nt * 64;
    smean_s[t] = s_mean[b * CC + t];
    if (ct == 0) {
        for (int e = t; e < 2048; e += 256) ws[e] = qW[e];
        if (t < 64) bs[t] = qB[t];
    }
#pragma unroll
    for (int p = 0; p < 4; ++p) {
        int e = t + p * 256;
        int c = e >> 4, n4 = (e & 15) * 4;
        float4 v = *(const float4*)&Xb[(size_t)c * NP + n4];
        tile[c][n4] = v.x; tile[c][n4 + 1] = v.y; tile[c][n4 + 2] = v.z; tile[c][n4 + 3] = v.w;
    }
    __syncthreads();
    if (t < 64) {
        float a = fc1_b[t];
#pragma unroll 4
        for (int c = 0; c < CC; ++c) a += fc1_w[t * CC + c] * smean_s[c];
        h1[t] = fmaxf(a, 0.f);
    }
    __syncthreads();
    if (t < 64) {
        int c = ct * 64 + t;
        float a = fc2_b[c];
#pragma unroll 8
        for (int j = 0; j < 64; ++j) a += fc2_w[c * 64 + j] * h1[j];
        sig_l[t] = 1.f / (1.f + __expf(-a));
    }
    __syncthreads();
    u16* Yb = ygt + ((size_t)b * NP + nt * 64) * CC + ct * 64;
#pragma unroll
    for (int p = 0; p < 4; ++p) {
        int e = t + p * 256;
        int n = e >> 4, c4 = (e & 15) * 4;
        if (ct * 64 + c4 >= 32) {
            ushort4 o;
            o.x = f2bf(tile[c4][n] * sig_l[c4]);
            o.y = f2bf(tile[c4 + 1][n] * sig_l[c4 + 1]);
            o.z = f2bf(tile[c4 + 2][n] * sig_l[c4 + 2]);
            o.w = f2bf(tile[c4 + 3][n] * sig_l[c4 + 3]);
            *(ushort4*)&Yb[(size_t)n * CC + c4] = o;
        }
    }
    if (ct == 0) {
        int nn = t & 63, g = t >> 6;
        int n = nt * 64 + nn;
        float xs[32];
#pragma unroll
        for (int c = 0; c < 32; ++c) xs[c] = tile[c][nn] * sig_l[c];
        float acc[16];
#pragma unroll
        for (int oc = 0; oc < 16; ++oc) {
            int o = g * 16 + oc;
            float a = bs[o];
#pragma unroll
            for (int c = 0; c < 32; ++c) a += ws[o * 32 + c] * xs[c];
            acc[oc] = a;
        }
        if (g == 0) {
            u16* qr = Qt + ((size_t)b * NP + n) * 32;
            ushort4 z4; z4.x = 0; z4.y = 0; z4.z = 0; z4.w = 0;
#pragma unroll
            for (int j = 0; j < 16; j += 4) {
                ushort4 o4;
                o4.x = f2bf(acc[j] * 0.25f);     o4.y = f2bf(acc[j + 1] * 0.25f);
                o4.z = f2bf(acc[j + 2] * 0.25f); o4.w = f2bf(acc[j + 3] * 0.25f);
                *(ushort4*)&qr[j] = o4;
            }
            *(ushort4*)&qr[16] = z4; *(ushort4*)&qr[20] = z4;
            *(ushort4*)&qr[24] = z4; *(ushort4*)&qr[28] = z4;
        } else if (g == 1) {
            u16* kr = Kt + ((size_t)b * NP + n) * 32;
            ushort4 z4; z4.x = 0; z4.y = 0; z4.z = 0; z4.w = 0;
#pragma unroll
            for (int j = 0; j < 16; j += 4) {
                ushort4 k4;
                k4.x = f2bf(acc[j]);     k4.y = f2bf(acc[j + 1]);
                k4.z = f2bf(acc[j + 2]); k4.w = f2bf(acc[j + 3]);
                *(ushort4*)&kr[j] = k4;
            }
            *(ushort4*)&kr[16] = z4; *(ushort4*)&kr[20] = z4;
            *(ushort4*)&kr[24] = z4; *(ushort4*)&kr[28] = z4;
        } else {
#pragma unroll
            for (int oc = 0; oc < 16; ++oc) vtile[(g - 2) * 16 + oc][nn] = acc[oc];
        }
        __syncthreads();
        for (int e = t; e < 2048; e += 256) {
            int c = e >> 6, nn2 = e & 63;
            Vb[(size_t)b * 32 * NP + (size_t)c * NP + nt * 64 + nn2] = f2bf(vtile[c][nn2]);
        }
    }
}

// ---------------- MFMA flash attention + fused proj ----------------
__global__ __launch_bounds__(256)
void attn_mfma_kernel(const u16* __restrict__ Qt, const u16* __restrict__ Kt,
                      const u16* __restrict__ Vb,
                      const float* __restrict__ proj_w, const float* __restrict__ proj_b,
                      u16* __restrict__ ygt) {
    int b = blockIdx.x >> 6;
    int n0 = (blockIdx.x & 63) * 16;
    __shared__ __align__(16) u16 P_lds[4][16][40];
    __shared__ float al_lds[4][16];
    __shared__ float sm_lds[4][16];
    __shared__ float sl_lds[4][16];
    __shared__ float O_lds[4][16][33];
    __shared__ float pw_s[32][32];
    __shared__ float pb_s[32];
    int t = threadIdx.x;
    int w = t >> 6, lane = t & 63;
    int q = lane >> 4, idx = lane & 15;

    for (int e = t; e < 1024; e += 256) pw_s[e >> 5][e & 31] = proj_w[e];
    if (t < 32) pb_s[t] = proj_b[t];
    __syncthreads();

    const u16* Qb = Qt + (size_t)b * NP * 32;
    const u16* Kb = Kt + (size_t)b * NP * 32;
    const u16* Vp = Vb + (size_t)b * 32 * NP;

    int nrow = n0 + idx;
    bf16x8 aq = *(const bf16x8*)&Qb[(size_t)nrow * 32 + q * 8];

    f32x4 O0 = {0.f, 0.f, 0.f, 0.f}, O1 = {0.f, 0.f, 0.f, 0.f};
    float m_run[4] = {-1e30f, -1e30f, -1e30f, -1e30f};
    float l_run[4] = {0.f, 0.f, 0.f, 0.f};

    int mbase = w * 256;
    for (int m0 = mbase; m0 < mbase + 256; m0 += 32) {
        bf16x8 bk0 = *(const bf16x8*)&Kb[(size_t)(m0 + idx) * 32 + q * 8];
        bf16x8 bk1 = *(const bf16x8*)&Kb[(size_t)(m0 + 16 + idx) * 32 + q * 8];
        bf16x8 va0 = *(const bf16x8*)&Vp[(size_t)idx * NP + m0 + q * 8];
        bf16x8 va1 = *(const bf16x8*)&Vp[(size_t)(16 + idx) * NP + m0 + q * 8];
        f32x4 z = {0.f, 0.f, 0.f, 0.f};
        f32x4 S0 = __builtin_amdgcn_mfma_f32_16x16x32_bf16(aq, bk0, z, 0, 0, 0);
        f32x4 S1 = __builtin_amdgcn_mfma_f32_16x16x32_bf16(aq, bk1, z, 0, 0, 0);
        float mx[4], p0[4], p1[4], alpha[4];
#pragma unroll
        for (int r = 0; r < 4; ++r) mx[r] = fmaxf(S0[r], S1[r]);
#pragma unroll
        for (int off = 1; off < 16; off <<= 1)
#pragma unroll
            for (int r = 0; r < 4; ++r) mx[r] = fmaxf(mx[r], __shfl_xor(mx[r], off, 64));
#pragma unroll
        for (int r = 0; r < 4; ++r) {
            float nm = fmaxf(m_run[r], mx[r]);
            alpha[r] = __expf(m_run[r] - nm);
            m_run[r] = nm;
            p0[r] = __expf(S0[r] - nm);
            p1[r] = __expf(S1[r] - nm);
        }
#pragma unroll
        for (int r = 0; r < 4; ++r) {
            float s = p0[r] + p1[r];
#pragma unroll
            for (int off = 1; off < 16; off <<= 1) s += __shfl_xor(s, off, 64);
            l_run[r] = l_run[r] * alpha[r] + s;
        }
#pragma unroll
        for (int r = 0; r < 4; ++r) {
            P_lds[w][q * 4 + r][idx]      = f2bf(p0[r]);
            P_lds[w][q * 4 + r][idx + 16] = f2bf(p1[r]);
        }
        if (idx == 0) {
#pragma unroll
            for (int r = 0; r < 4; ++r) al_lds[w][q * 4 + r] = alpha[r];
        }
        float an = al_lds[w][idx];
#pragma unroll
        for (int r = 0; r < 4; ++r) { O0[r] *= an; O1[r] *= an; }
        bf16x8 pf = *(const bf16x8*)&P_lds[w][idx][q * 8];
        O0 = __builtin_amdgcn_mfma_f32_16x16x32_bf16(va0, pf, O0, 0, 0, 0);
        O1 = __builtin_amdgcn_mfma_f32_16x16x32_bf16(va1, pf, O1, 0, 0, 0);
    }
    if (idx == 0) {
#pragma unroll
        for (int r = 0; r < 4; ++r) {
            sm_lds[w][q * 4 + r] = m_run[r];
            sl_lds[w][q * 4 + r] = l_run[r];
        }
    }
#pragma unroll
    for (int r = 0; r < 4; ++r) {
        O_lds[w][idx][q * 4 + r]      = O0[r];
        O_lds[w][idx][q * 4 + r + 16] = O1[r];
    }
    __syncthreads();
    if (w == 0) {
        float m0_ = sm_lds[0][idx], m1 = sm_lds[1][idx], m2 = sm_lds[2][idx], m3 = sm_lds[3][idx];
        float gm = fmaxf(fmaxf(m0_, m1), fmaxf(m2, m3));
        float e0 = __expf(m0_ - gm), e1 = __expf(m1 - gm);
        float e2 = __expf(m2 - gm), e3 = __expf(m3 - gm);
        float linv = 1.f / (sl_lds[0][idx] * e0 + sl_lds[1][idx] * e1 +
                            sl_lds[2][idx] * e2 + sl_lds[3][idx] * e3);
#pragma unroll
        for (int r = 0; r < 4; ++r) {
            int c0 = q * 4 + r;
            O_lds[0][idx][c0] = (O_lds[0][idx][c0] * e0 + O_lds[1][idx][c0] * e1 +
                                 O_lds[2][idx][c0] * e2 + O_lds[3][idx][c0] * e3) * linv;
            int c1 = c0 + 16;
            O_lds[0][idx][c1] = (O_lds[0][idx][c1] * e0 + O_lds[1][idx][c1] * e1 +
                                 O_lds[2][idx][c1] * e2 + O_lds[3][idx][c1] * e3) * linv;
        }
        float o0[4], o1[4];
#pragma unroll
        for (int r = 0; r < 4; ++r) { o0[r] = pb_s[q * 4 + r]; o1[r] = pb_s[q * 4 + r + 16]; }
#pragma unroll
        for (int c = 0; c < 32; ++c) {
            float xv = O_lds[0][idx][c];
#pragma unroll
            for (int r = 0; r < 4; ++r) {
                o0[r] += pw_s[q * 4 + r][c] * xv;
                o1[r] += pw_s[q * 4 + r + 16][c] * xv;
            }
        }
        u16* yrow = ygt + ((size_t)b * NP + n0 + idx) * CC;
        ushort4 w0, w1;
        w0.x = f2bf(o0[0]); w0.y = f2bf(o0[1]); w0.z = f2bf(o0[2]); w0.w = f2bf(o0[3]);
        w1.x = f2bf(o1[0]); w1.y = f2bf(o1[1]); w1.z = f2bf(o1[2]); w1.w = f2bf(o1[3]);
        *(ushort4*)&yrow[q * 4] = w0;
        *(ushort4*)&yrow[q * 4 + 16] = w1;
    }
}

// ---------------- bf16 MFMA GEMM, 128x128 tile, BK=64, double-buffered ----------------
template <int K, bool RELU>
__global__ __launch_bounds__(256)
void mfma_gemm_kernel(const u16* __restrict__ A, const u16* __restrict__ Bt,
                      const float* __restrict__ bias, u16* __restrict__ Y, int M) {
    __shared__ __align__(16) u16 As[2][128][64];
    __shared__ __align__(16) u16 Bs[2][128][64];
    constexpr int NIT = K / 64;
    int mt = blockIdx.x, nt = blockIdx.y;
    const u16* Ab = A + (size_t)mt * 128 * K;
    const u16* Bb = Bt + (size_t)nt * 128 * K;
    int t = threadIdx.x;
    int w = t >> 6, lane = t & 63;
    int q = lane >> 4, idx = lane & 15;
    int wr = (w >> 1) * 64, wc = (w & 1) * 64;
    int srow = lane >> 3;
    int gch = (lane & 7) ^ srow;

    f32x4 acc[4][4];
#pragma unroll
    for (int i = 0; i < 4; ++i)
#pragma unroll
        for (int j = 0; j < 4; ++j) { f32x4 z = {0.f, 0.f, 0.f, 0.f}; acc[i][j] = z; }

#define ISSUE_LOADS(buf, k0)                                                              \
    {                                                                                     \
        _Pragma("unroll")                                                                 \
        for (int p = 0; p < 4; ++p) {                                                     \
            int r = w * 32 + p * 8 + srow;                                                \
            __builtin_amdgcn_global_load_lds(                                             \
                (const __attribute__((address_space(1))) void*)(Ab + (size_t)r * K + (k0) + gch * 8), \
                (__attribute__((address_space(3))) void*)(&As[buf][w * 32 + p * 8][0]),   \
                16, 0, 0);                                                                \
        }                                                                                 \
        _Pragma("unroll")                                                                 \
        for (int p = 0; p < 4; ++p) {                                                     \
            int r = w * 32 + p * 8 + srow;                                                \
            __builtin_amdgcn_global_load_lds(                                             \
                (const __attribute__((address_space(1))) void*)(Bb + (size_t)r * K + (k0) + gch * 8), \
                (__attribute__((address_space(3))) void*)(&Bs[buf][w * 32 + p * 8][0]),   \
                16, 0, 0);                                                                \
        }                                                                                 \
    }

    ISSUE_LOADS(0, 0)
    for (int ki = 0; ki < NIT; ++ki) {
        int cur = ki & 1;
        __syncthreads();
        if (ki + 1 < NIT) ISSUE_LOADS(cur ^ 1, (ki + 1) * 64)
#pragma unroll
        for (int h = 0; h < 2; ++h) {
            bf16x8 af[4], bfr[4];
#pragma unroll
            for (int i = 0; i < 4; ++i)
                af[i] = *(const bf16x8*)&As[cur][wr + i * 16 + idx][(((q + 4 * h) ^ (idx & 7)) * 8)];
#pragma unroll
            for (int j = 0; j < 4; ++j)
                bfr[j] = *(const bf16x8*)&Bs[cur][wc + j * 16 + idx][(((q + 4 * h) ^ (idx & 7)) * 8)];
#pragma unroll
            for (int i = 0; i < 4; ++i)
#pragma unroll
                for (int j = 0; j < 4; ++j)
                    acc[i][j] = __builtin_amdgcn_mfma_f32_16x16x32_bf16(af[i], bfr[j], acc[i][j], 0, 0, 0);
        }
    }
#undef ISSUE_LOADS

    // bf16 transposed output Y[n][m] with bias(+ReLU)
#pragma unroll
    for (int i = 0; i < 4; ++i) {
        int m0 = mt * 128 + wr + i * 16 + q * 4;
        float b0 = bias[m0], b1 = bias[m0 + 1], b2 = bias[m0 + 2], b3 = bias[m0 + 3];
#pragma unroll
        for (int j = 0; j < 4; ++j) {
            int n = nt * 128 + wc + j * 16 + idx;
            f32x4 v = acc[i][j];
            float r0 = v.x + b0, r1 = v.y + b1, r2 = v.z + b2, r3 = v.w + b3;
            if (RELU) {
                r0 = fmaxf(r0, 0.f); r1 = fmaxf(r1, 0.f);
                r2 = fmaxf(r2, 0.f); r3 = fmaxf(r3, 0.f);
            }
            ushort4 o;
            o.x = f2bf(r0); o.y = f2bf(r1); o.z = f2bf(r2); o.w = f2bf(r3);
            *(ushort4*)&Y[(size_t)n * (size_t)M + m0] = o;
        }
    }
}

// ---------------- bf16 MFMA GEMM, 128x64 tile (fp32 out), BK=64, double-buffered ----------------
template <int K>
__global__ __launch_bounds__(256)
void mfma_gemm_n64_kernel(const u16* __restrict__ A, const u16* __restrict__ Bt,
                          const float* __restrict__ bias, float* __restrict__ Y, int M) {
    __shared__ __align__(16) u16 As[2][128][64];
    __shared__ __align__(16) u16 Bs[2][64][64];
    constexpr int NIT = K / 64;
    int mt = blockIdx.x, nt = blockIdx.y;
    const u16* Ab = A + (size_t)mt * 128 * K;
    const u16* Bb = Bt + (size_t)nt * 64 * K;
    int t = threadIdx.x;
    int w = t >> 6, lane = t & 63;
    int q = lane >> 4, idx = lane & 15;
    int wr = (w >> 1) * 64, wc = (w & 1) * 32;
    int srow = lane >> 3;
    int gch = (lane & 7) ^ srow;

    f32x4 acc[4][2];
#pragma unroll
    for (int i = 0; i < 4; ++i)
#pragma unroll
        for (int j = 0; j < 2; ++j) { f32x4 z = {0.f, 0.f, 0.f, 0.f}; acc[i][j] = z; }

#define ISSUE_LOADS64(buf, k0)                                                            \
    {                                                                                     \
        _Pragma("unroll")                                                                 \
        for (int p = 0; p < 4; ++p) {                                                     \
            int r = w * 32 + p * 8 + srow;                                                \
            __builtin_amdgcn_global_load_lds(                                             \
                (const __attribute__((address_space(1))) void*)(Ab + (size_t)r * K + (k0) + gch * 8), \
                (__attribute__((address_space(3))) void*)(&As[buf][w * 32 + p * 8][0]),   \
                16, 0, 0);                                                                \
        }                                                                                 \
        _Pragma("unroll")                                                                 \
        for (int p = 0; p < 2; ++p) {                                                     \
            int r = w * 16 + p * 8 + srow;                                                \
            __builtin_amdgcn_global_load_lds(                                             \
                (const __attribute__((address_space(1))) void*)(Bb + (size_t)r * K + (k0) + gch * 8), \
                (__attribute__((address_space(3))) void*)(&Bs[buf][w * 16 + p * 8][0]),   \
                16, 0, 0);                                                                \
        }                                                                                 \
    }

    ISSUE_LOADS64(0, 0)
    for (int ki = 0; ki < NIT; ++ki) {
        int cur = ki & 1;
        __syncthreads();
        if (ki + 1 < NIT) ISSUE_LOADS64(cur ^ 1, (ki + 1) * 64)
#pragma unroll
        for (int h = 0; h < 2; ++h) {
            bf16x8 af[4], bfr[2];
#pragma unroll
            for (int i = 0; i < 4; ++i)
                af[i] = *(const bf16x8*)&As[cur][wr + i * 16 + idx][(((q + 4 * h) ^ (idx & 7)) * 8)];
#pragma unroll
            for (int j = 0; j < 2; ++j)
                bfr[j] = *(const bf16x8*)&Bs[cur][wc + j * 16 + idx][(((q + 4 * h) ^ (idx & 7)) * 8)];
#pragma unroll
            for (int i = 0; i < 4; ++i)
#pragma unroll
                for (int j = 0; j < 2; ++j)
                    acc[i][j] = __builtin_amdgcn_mfma_f32_16x16x32_bf16(af[i], bfr[j], acc[i][j], 0, 0, 0);
        }
    }
#undef ISSUE_LOADS64

    // fp32 output Y[b][m][n]
#pragma unroll
    for (int i = 0; i < 4; ++i) {
        int m0 = mt * 128 + wr + i * 16 + q * 4;
        float b0 = bias[m0], b1 = bias[m0 + 1], b2 = bias[m0 + 2], b3 = bias[m0 + 3];
#pragma unroll
        for (int j = 0; j < 2; ++j) {
            int ng = nt * 64 + wc + j * 16 + idx;
            int bb = ng >> 10, nn = ng & 1023;
            f32x4 v = acc[i][j];
            float* p = Y + ((size_t)bb * M + m0) * NP + nn;
            p[0]      = v.x + b0;
            p[NP]     = v.y + b1;
            p[2 * NP] = v.z + b2;
            p[3 * NP] = v.w + b3;
        }
    }
}

extern "C" void kernel_launch(void* const* d_in, const int* in_sizes, int n_in,
                              void* d_out, int out_size, void* d_ws, size_t ws_size,
                              hipStream_t stream) {
    const float* x      = (const float*)d_in[0];
    const float* fc1_w  = (const float*)d_in[1];
    const float* fc1_b  = (const float*)d_in[2];
    const float* fc2_w  = (const float*)d_in[3];
    const float* fc2_b  = (const float*)d_in[4];
    const float* qkv_w  = (const float*)d_in[5];
    const float* qkv_b  = (const float*)d_in[6];
    const float* proj_w = (const float*)d_in[7];
    const float* proj_b = (const float*)d_in[8];
    const float* ffn1_w = (const float*)d_in[9];
    const float* ffn1_b = (const float*)d_in[10];
    const float* ffn2_w = (const float*)d_in[11];
    const float* ffn2_b = (const float*)d_in[12];
    float* out = (float*)d_out;

    // layout: [w1b 512K][w2b 512K][ygt 8M][ht 32M]; pre-FFN buffers overlap ht (dead by FFN1)
    u16* w1b = (u16*)d_ws;
    u16* w2b = w1b + 262144;
    u16* ygt = w2b + 262144;                         // [b*1024][256] bf16
    u16* ht  = ygt + (size_t)BB * NP * CC;           // [b*1024][1024] bf16
    float* s_mean = (float*)ht;                      // 16 KB
    u16* Qt = (u16*)(s_mean + BB * CC);              // 1 MB
    u16* Kt = Qt + (size_t)BB * NP * 32;             // 1 MB
    u16* Vb = Kt + (size_t)BB * NP * 32;             // 1 MB

    se_mean_conv_kernel<<<BB * CC + 512, 256, 0, stream>>>(x, s_mean, ffn1_w, w1b, ffn2_w, w2b);
    scale_transpose_qkv_kernel<<<dim3(16, 4, BB), 256, 0, stream>>>(
        x, s_mean, fc1_w, fc1_b, fc2_w, fc2_b, qkv_w, qkv_b, ygt, Qt, Kt, Vb);
    attn_mfma_kernel<<<BB * 64, 256, 0, stream>>>(Qt, Kt, Vb, proj_w, proj_b, ygt);

    // FFN1: ht[nflat][1024] bf16 (ReLU) = ffn1_w(1024x256) @ ygt
    mfma_gemm_kernel<256, true><<<dim3(8, 128), 256, 0, stream>>>(
        w1b, ygt, ffn1_b, ht, 1024);
    // FFN2: out[b][256][1024] fp32 = ffn2_w(256x1024) @ ht  (128x64 tiles, 2 blocks/CU)
    mfma_gemm_n64_kernel<1024><<<dim3(2, 256), 256, 0, stream>>>(
        w2b, ht, ffn2_b, out, 256);
}

// Round 9
// 181.884 us; speedup vs baseline: 1.1084x; 1.0028x over previous
//
#include <hip/hip_runtime.h>
#include <cstdint>
#include <cstddef>

#define BB 16
#define CC 256
#define NP 1024   // H*W

typedef __attribute__((ext_vector_type(8))) short bf16x8;
typedef __attribute__((ext_vector_type(4))) float f32x4;
typedef unsigned short u16;

__device__ __forceinline__ u16 f2bf(float f) {
    union { float f; uint32_t u; } v; v.f = f;
    uint32_t u = v.u;
    return (u16)((u + 0x7FFFu + ((u >> 16) & 1u)) >> 16);   // RNE
}

// ---------------- SE mean (blocks 0..4095) + weight convert (blocks 4096..4607) ----------------
__global__ __launch_bounds__(256)
void se_mean_conv_kernel(const float* __restrict__ x, float* __restrict__ s_mean,
                         const float* __restrict__ w1, u16* __restrict__ d1,
                         const float* __restrict__ w2, u16* __restrict__ d2) {
    int blk = blockIdx.x;
    int t = threadIdx.x;
    if (blk < BB * CC) {
        const float* p = x + (size_t)blk * NP;
        float4 v = *(const float4*)(p + t * 4);
        float s = (v.x + v.y) + (v.z + v.w);
#pragma unroll
        for (int off = 32; off; off >>= 1) s += __shfl_down(s, off, 64);
        __shared__ float red[4];
        if ((t & 63) == 0) red[t >> 6] = s;
        __syncthreads();
        if (t == 0) s_mean[blk] = (red[0] + red[1] + red[2] + red[3]) * (1.0f / NP);
    } else {
        int blk2 = blk - BB * CC;
        const float* src = (blk2 < 256) ? w1 : w2;
        u16* dst = (blk2 < 256) ? d1 : d2;
        int i = ((blk2 & 255) * 256 + t) * 4;
        float4 v = *(const float4*)(src + i);
        ushort4 o;
        o.x = f2bf(v.x); o.y = f2bf(v.y); o.z = f2bf(v.z); o.w = f2bf(v.w);
        *(ushort4*)(dst + i) = o;
    }
}

// ---- scale + transpose + per-block SE-mlp (+ fused qkv on ct==0 blocks) ----
__global__ __launch_bounds__(256)
void scale_transpose_qkv_kernel(const float* __restrict__ x, const float* __restrict__ s_mean,
                                const float* __restrict__ fc1_w, const float* __restrict__ fc1_b,
                                const float* __restrict__ fc2_w, const float* __restrict__ fc2_b,
                                const float* __restrict__ qW, const float* __restrict__ qB,
                                u16* __restrict__ ygt, u16* __restrict__ Qt,
                                u16* __restrict__ Kt, u16* __restrict__ Vb) {
    // grid: (16 nt, 4 ct, BB)
    int nt = blockIdx.x, ct = blockIdx.y, b = blockIdx.z;
    __shared__ float tile[64][65];
    __shared__ float ws[64 * 32];
    __shared__ float bs[64];
    __shared__ float vtile[32][64];
    __shared__ float smean_s[CC];
    __shared__ float h1[64];
    __shared__ float sig_l[64];
    int t = threadIdx.x;
    const float* Xb = x + ((size_t)b * CC + ct * 64) * NP + nt * 64;
    smean_s[t] = s_mean[b * CC + t];
    if (ct == 0) {
        for (int e = t; e < 2048; e += 256) ws[e] = qW[e];
        if (t < 64) bs[t] = qB[t];
    }
#pragma unroll
    for (int p = 0; p < 4; ++p) {
        int e = t + p * 256;
        int c = e >> 4, n4 = (e & 15) * 4;
        float4 v = *(const float4*)&Xb[(size_t)c * NP + n4];
        tile[c][n4] = v.x; tile[c][n4 + 1] = v.y; tile[c][n4 + 2] = v.z; tile[c][n4 + 3] = v.w;
    }
    __syncthreads();
    if (t < 64) {
        float a = fc1_b[t];
#pragma unroll 4
        for (int c = 0; c < CC; ++c) a += fc1_w[t * CC + c] * smean_s[c];
        h1[t] = fmaxf(a, 0.f);
    }
    __syncthreads();
    if (t < 64) {
        int c = ct * 64 + t;
        float a = fc2_b[c];
#pragma unroll 8
        for (int j = 0; j < 64; ++j) a += fc2_w[c * 64 + j] * h1[j];
        sig_l[t] = 1.f / (1.f + __expf(-a));
    }
    __syncthreads();
    u16* Yb = ygt + ((size_t)b * NP + nt * 64) * CC + ct * 64;
#pragma unroll
    for (int p = 0; p < 4; ++p) {
        int e = t + p * 256;
        int n = e >> 4, c4 = (e & 15) * 4;
        if (ct * 64 + c4 >= 32) {
            ushort4 o;
            o.x = f2bf(tile[c4][n] * sig_l[c4]);
            o.y = f2bf(tile[c4 + 1][n] * sig_l[c4 + 1]);
            o.z = f2bf(tile[c4 + 2][n] * sig_l[c4 + 2]);
            o.w = f2bf(tile[c4 + 3][n] * sig_l[c4 + 3]);
            *(ushort4*)&Yb[(size_t)n * CC + c4] = o;
        }
    }
    if (ct == 0) {
        int nn = t & 63, g = t >> 6;
        int n = nt * 64 + nn;
        float xs[32];
#pragma unroll
        for (int c = 0; c < 32; ++c) xs[c] = tile[c][nn] * sig_l[c];
        float acc[16];
#pragma unroll
        for (int oc = 0; oc < 16; ++oc) {
            int o = g * 16 + oc;
            float a = bs[o];
#pragma unroll
            for (int c = 0; c < 32; ++c) a += ws[o * 32 + c] * xs[c];
            acc[oc] = a;
        }
        if (g == 0) {
            u16* qr = Qt + ((size_t)b * NP + n) * 32;
            ushort4 z4; z4.x = 0; z4.y = 0; z4.z = 0; z4.w = 0;
#pragma unroll
            for (int j = 0; j < 16; j += 4) {
                ushort4 o4;
                o4.x = f2bf(acc[j] * 0.25f);     o4.y = f2bf(acc[j + 1] * 0.25f);
                o4.z = f2bf(acc[j + 2] * 0.25f); o4.w = f2bf(acc[j + 3] * 0.25f);
                *(ushort4*)&qr[j] = o4;
            }
            *(ushort4*)&qr[16] = z4; *(ushort4*)&qr[20] = z4;
            *(ushort4*)&qr[24] = z4; *(ushort4*)&qr[28] = z4;
        } else if (g == 1) {
            u16* kr = Kt + ((size_t)b * NP + n) * 32;
            ushort4 z4; z4.x = 0; z4.y = 0; z4.z = 0; z4.w = 0;
#pragma unroll
            for (int j = 0; j < 16; j += 4) {
                ushort4 k4;
                k4.x = f2bf(acc[j]);     k4.y = f2bf(acc[j + 1]);
                k4.z = f2bf(acc[j + 2]); k4.w = f2bf(acc[j + 3]);
                *(ushort4*)&kr[j] = k4;
            }
            *(ushort4*)&kr[16] = z4; *(ushort4*)&kr[20] = z4;
            *(ushort4*)&kr[24] = z4; *(ushort4*)&kr[28] = z4;
        } else {
#pragma unroll
            for (int oc = 0; oc < 16; ++oc) vtile[(g - 2) * 16 + oc][nn] = acc[oc];
        }
        __syncthreads();
        for (int e = t; e < 2048; e += 256) {
            int c = e >> 6, nn2 = e & 63;
            Vb[(size_t)b * 32 * NP + (size_t)c * NP + nt * 64 + nn2] = f2bf(vtile[c][nn2]);
        }
    }
}

// ---------------- MFMA flash attention + fused proj ----------------
__global__ __launch_bounds__(256)
void attn_mfma_kernel(const u16* __restrict__ Qt, const u16* __restrict__ Kt,
                      const u16* __restrict__ Vb,
                      const float* __restrict__ proj_w, const float* __restrict__ proj_b,
                      u16* __restrict__ ygt) {
    int b = blockIdx.x >> 6;
    int n0 = (blockIdx.x & 63) * 16;
    __shared__ __align__(16) u16 P_lds[4][16][40];
    __shared__ float al_lds[4][16];
    __shared__ float sm_lds[4][16];
    __shared__ float sl_lds[4][16];
    __shared__ float O_lds[4][16][33];
    __shared__ float pw_s[32][32];
    __shared__ float pb_s[32];
    int t = threadIdx.x;
    int w = t >> 6, lane = t & 63;
    int q = lane >> 4, idx = lane & 15;

    for (int e = t; e < 1024; e += 256) pw_s[e >> 5][e & 31] = proj_w[e];
    if (t < 32) pb_s[t] = proj_b[t];
    __syncthreads();

    const u16* Qb = Qt + (size_t)b * NP * 32;
    const u16* Kb = Kt + (size_t)b * NP * 32;
    const u16* Vp = Vb + (size_t)b * 32 * NP;

    int nrow = n0 + idx;
    bf16x8 aq = *(const bf16x8*)&Qb[(size_t)nrow * 32 + q * 8];

    f32x4 O0 = {0.f, 0.f, 0.f, 0.f}, O1 = {0.f, 0.f, 0.f, 0.f};
    float m_run[4] = {-1e30f, -1e30f, -1e30f, -1e30f};
    float l_run[4] = {0.f, 0.f, 0.f, 0.f};

    int mbase = w * 256;
    for (int m0 = mbase; m0 < mbase + 256; m0 += 32) {
        bf16x8 bk0 = *(const bf16x8*)&Kb[(size_t)(m0 + idx) * 32 + q * 8];
        bf16x8 bk1 = *(const bf16x8*)&Kb[(size_t)(m0 + 16 + idx) * 32 + q * 8];
        bf16x8 va0 = *(const bf16x8*)&Vp[(size_t)idx * NP + m0 + q * 8];
        bf16x8 va1 = *(const bf16x8*)&Vp[(size_t)(16 + idx) * NP + m0 + q * 8];
        f32x4 z = {0.f, 0.f, 0.f, 0.f};
        f32x4 S0 = __builtin_amdgcn_mfma_f32_16x16x32_bf16(aq, bk0, z, 0, 0, 0);
        f32x4 S1 = __builtin_amdgcn_mfma_f32_16x16x32_bf16(aq, bk1, z, 0, 0, 0);
        float mx[4], p0[4], p1[4], alpha[4];
#pragma unroll
        for (int r = 0; r < 4; ++r) mx[r] = fmaxf(S0[r], S1[r]);
#pragma unroll
        for (int off = 1; off < 16; off <<= 1)
#pragma unroll
            for (int r = 0; r < 4; ++r) mx[r] = fmaxf(mx[r], __shfl_xor(mx[r], off, 64));
#pragma unroll
        for (int r = 0; r < 4; ++r) {
            float nm = fmaxf(m_run[r], mx[r]);
            alpha[r] = __expf(m_run[r] - nm);
            m_run[r] = nm;
            p0[r] = __expf(S0[r] - nm);
            p1[r] = __expf(S1[r] - nm);
        }
#pragma unroll
        for (int r = 0; r < 4; ++r) {
            float s = p0[r] + p1[r];
#pragma unroll
            for (int off = 1; off < 16; off <<= 1) s += __shfl_xor(s, off, 64);
            l_run[r] = l_run[r] * alpha[r] + s;
        }
#pragma unroll
        for (int r = 0; r < 4; ++r) {
            P_lds[w][q * 4 + r][idx]      = f2bf(p0[r]);
            P_lds[w][q * 4 + r][idx + 16] = f2bf(p1[r]);
        }
        if (idx == 0) {
#pragma unroll
            for (int r = 0; r < 4; ++r) al_lds[w][q * 4 + r] = alpha[r];
        }
        float an = al_lds[w][idx];
#pragma unroll
        for (int r = 0; r < 4; ++r) { O0[r] *= an; O1[r] *= an; }
        bf16x8 pf = *(const bf16x8*)&P_lds[w][idx][q * 8];
        O0 = __builtin_amdgcn_mfma_f32_16x16x32_bf16(va0, pf, O0, 0, 0, 0);
        O1 = __builtin_amdgcn_mfma_f32_16x16x32_bf16(va1, pf, O1, 0, 0, 0);
    }
    if (idx == 0) {
#pragma unroll
        for (int r = 0; r < 4; ++r) {
            sm_lds[w][q * 4 + r] = m_run[r];
            sl_lds[w][q * 4 + r] = l_run[r];
        }
    }
#pragma unroll
    for (int r = 0; r < 4; ++r) {
        O_lds[w][idx][q * 4 + r]      = O0[r];
        O_lds[w][idx][q * 4 + r + 16] = O1[r];
    }
    __syncthreads();
    if (w == 0) {
        float m0_ = sm_lds[0][idx], m1 = sm_lds[1][idx], m2 = sm_lds[2][idx], m3 = sm_lds[3][idx];
        float gm = fmaxf(fmaxf(m0_, m1), fmaxf(m2, m3));
        float e0 = __expf(m0_ - gm), e1 = __expf(m1 - gm);
        float e2 = __expf(m2 - gm), e3 = __expf(m3 - gm);
        float linv = 1.f / (sl_lds[0][idx] * e0 + sl_lds[1][idx] * e1 +
                            sl_lds[2][idx] * e2 + sl_lds[3][idx] * e3);
#pragma unroll
        for (int r = 0; r < 4; ++r) {
            int c0 = q * 4 + r;
            O_lds[0][idx][c0] = (O_lds[0][idx][c0] * e0 + O_lds[1][idx][c0] * e1 +
                                 O_lds[2][idx][c0] * e2 + O_lds[3][idx][c0] * e3) * linv;
            int c1 = c0 + 16;
            O_lds[0][idx][c1] = (O_lds[0][idx][c1] * e0 + O_lds[1][idx][c1] * e1 +
                                 O_lds[2][idx][c1] * e2 + O_lds[3][idx][c1] * e3) * linv;
        }
        float o0[4], o1[4];
#pragma unroll
        for (int r = 0; r < 4; ++r) { o0[r] = pb_s[q * 4 + r]; o1[r] = pb_s[q * 4 + r + 16]; }
#pragma unroll
        for (int c = 0; c < 32; ++c) {
            float xv = O_lds[0][idx][c];
#pragma unroll
            for (int r = 0; r < 4; ++r) {
                o0[r] += pw_s[q * 4 + r][c] * xv;
                o1[r] += pw_s[q * 4 + r + 16][c] * xv;
            }
        }
        u16* yrow = ygt + ((size_t)b * NP + n0 + idx) * CC;
        ushort4 w0, w1;
        w0.x = f2bf(o0[0]); w0.y = f2bf(o0[1]); w0.z = f2bf(o0[2]); w0.w = f2bf(o0[3]);
        w1.x = f2bf(o1[0]); w1.y = f2bf(o1[1]); w1.z = f2bf(o1[2]); w1.w = f2bf(o1[3]);
        *(ushort4*)&yrow[q * 4] = w0;
        *(ushort4*)&yrow[q * 4 + 16] = w1;
    }
}

// ---------------- FFN1: bf16 MFMA GEMM, 128x128 tile, BK=64, dbuf, LDS-bounced epilogue ----------------
// Y[n][m] bf16 (+bias+ReLU), written via LDS tile with XOR-16B swizzle -> 16 B/lane coalesced stores.
template <int K>
__global__ __launch_bounds__(256)
void mfma_gemm_kernel(const u16* __restrict__ A, const u16* __restrict__ Bt,
                      const float* __restrict__ bias, u16* __restrict__ Y, int M) {
    __shared__ __align__(16) u16 As[2][128][64];
    __shared__ __align__(16) u16 Bs[2][128][64];
    constexpr int NIT = K / 64;
    int mt = blockIdx.x, nt = blockIdx.y;
    const u16* Ab = A + (size_t)mt * 128 * K;
    const u16* Bb = Bt + (size_t)nt * 128 * K;
    int t = threadIdx.x;
    int w = t >> 6, lane = t & 63;
    int q = lane >> 4, idx = lane & 15;
    int wr = (w >> 1) * 64, wc = (w & 1) * 64;
    int srow = lane >> 3;
    int gch = (lane & 7) ^ srow;

    f32x4 acc[4][4];
#pragma unroll
    for (int i = 0; i < 4; ++i)
#pragma unroll
        for (int j = 0; j < 4; ++j) { f32x4 z = {0.f, 0.f, 0.f, 0.f}; acc[i][j] = z; }

#define ISSUE_LOADS(buf, k0)                                                              \
    {                                                                                     \
        _Pragma("unroll")                                                                 \
        for (int p = 0; p < 4; ++p) {                                                     \
            int r = w * 32 + p * 8 + srow;                                                \
            __builtin_amdgcn_global_load_lds(                                             \
                (const __attribute__((address_space(1))) void*)(Ab + (size_t)r * K + (k0) + gch * 8), \
                (__attribute__((address_space(3))) void*)(&As[buf][w * 32 + p * 8][0]),   \
                16, 0, 0);                                                                \
        }                                                                                 \
        _Pragma("unroll")                                                                 \
        for (int p = 0; p < 4; ++p) {                                                     \
            int r = w * 32 + p * 8 + srow;                                                \
            __builtin_amdgcn_global_load_lds(                                             \
                (const __attribute__((address_space(1))) void*)(Bb + (size_t)r * K + (k0) + gch * 8), \
                (__attribute__((address_space(3))) void*)(&Bs[buf][w * 32 + p * 8][0]),   \
                16, 0, 0);                                                                \
        }                                                                                 \
    }

    ISSUE_LOADS(0, 0)
    for (int ki = 0; ki < NIT; ++ki) {
        int cur = ki & 1;
        __syncthreads();
        if (ki + 1 < NIT) ISSUE_LOADS(cur ^ 1, (ki + 1) * 64)
#pragma unroll
        for (int h = 0; h < 2; ++h) {
            bf16x8 af[4], bfr[4];
#pragma unroll
            for (int i = 0; i < 4; ++i)
                af[i] = *(const bf16x8*)&As[cur][wr + i * 16 + idx][(((q + 4 * h) ^ (idx & 7)) * 8)];
#pragma unroll
            for (int j = 0; j < 4; ++j)
                bfr[j] = *(const bf16x8*)&Bs[cur][wc + j * 16 + idx][(((q + 4 * h) ^ (idx & 7)) * 8)];
#pragma unroll
            for (int i = 0; i < 4; ++i)
#pragma unroll
                for (int j = 0; j < 4; ++j)
                    acc[i][j] = __builtin_amdgcn_mfma_f32_16x16x32_bf16(af[i], bfr[j], acc[i][j], 0, 0, 0);
        }
    }
#undef ISSUE_LOADS

    // epilogue: bias+ReLU -> LDS tile [128 n][16 chunks, XOR(n&7)-swizzled] -> coalesced stores
    __syncthreads();                     // all MFMA LDS reads done; reuse As as tile
    u16* tile = &As[0][0][0];            // 128 rows x 256 B = 32 KB
#pragma unroll
    for (int i = 0; i < 4; ++i) {
        int m0 = wr + i * 16 + q * 4;    // local m
        int gm = mt * 128 + m0;
        float b0 = bias[gm], b1 = bias[gm + 1], b2 = bias[gm + 2], b3 = bias[gm + 3];
        int c16 = m0 >> 3;
        int off = (q & 1) * 4;
#pragma unroll
        for (int j = 0; j < 4; ++j) {
            int nl = wc + j * 16 + idx;  // local n
            f32x4 v = acc[i][j];
            ushort4 o;
            o.x = f2bf(fmaxf(v.x + b0, 0.f)); o.y = f2bf(fmaxf(v.y + b1, 0.f));
            o.z = f2bf(fmaxf(v.z + b2, 0.f)); o.w = f2bf(fmaxf(v.w + b3, 0.f));
            int cs = c16 ^ (nl & 7);
            *(ushort4*)&tile[nl * 128 + cs * 8 + off] = o;
        }
    }
    __syncthreads();
#pragma unroll
    for (int p = 0; p < 8; ++p) {
        int flat = p * 256 + t;          // 2048 chunk-copies of 16 B
        int n = flat >> 4, c = flat & 15;
        int cs = c ^ (n & 7);
        bf16x8 v = *(const bf16x8*)&tile[n * 128 + cs * 8];
        *(bf16x8*)&Y[((size_t)(nt * 128 + n)) * (size_t)M + mt * 128 + c * 8] = v;
    }
}

// ---------------- FFN2: bf16 MFMA GEMM, 64x64 tile, BK=64, dbuf, fp32 out ----------------
// grid (4, 256) = 1024 blocks -> ~5 blocks/CU (32 KB LDS): TLP hides staging latency.
template <int K>
__global__ __launch_bounds__(256)
void mfma_gemm_64_kernel(const u16* __restrict__ A, const u16* __restrict__ Bt,
                         const float* __restrict__ bias, float* __restrict__ Y, int M) {
    __shared__ __align__(16) u16 As[2][64][64];
    __shared__ __align__(16) u16 Bs[2][64][64];
    constexpr int NIT = K / 64;
    int mt = blockIdx.x, nt = blockIdx.y;
    const u16* Ab = A + (size_t)mt * 64 * K;
    const u16* Bb = Bt + (size_t)nt * 64 * K;
    int t = threadIdx.x;
    int w = t >> 6, lane = t & 63;
    int q = lane >> 4, idx = lane & 15;
    int wr = (w >> 1) * 32, wc = (w & 1) * 32;
    int srow = lane >> 3;                // 0..7
    int gch = (lane & 7) ^ srow;

    f32x4 acc[2][2];
#pragma unroll
    for (int i = 0; i < 2; ++i)
#pragma unroll
        for (int j = 0; j < 2; ++j) { f32x4 z = {0.f, 0.f, 0.f, 0.f}; acc[i][j] = z; }

#define ISSUE_LOADS64(buf, k0)                                                            \
    {                                                                                     \
        _Pragma("unroll")                                                                 \
        for (int p = 0; p < 2; ++p) {                                                     \
            int r = w * 16 + p * 8 + srow;                                                \
            __builtin_amdgcn_global_load_lds(                                             \
                (const __attribute__((address_space(1))) void*)(Ab + (size_t)r * K + (k0) + gch * 8), \
                (__attribute__((address_space(3))) void*)(&As[buf][w * 16 + p * 8][0]),   \
                16, 0, 0);                                                                \
        }                                                                                 \
        _Pragma("unroll")                                                                 \
        for (int p = 0; p < 2; ++p) {                                                     \
            int r = w * 16 + p * 8 + srow;                                                \
            __builtin_amdgcn_global_load_lds(                                             \
                (const __attribute__((address_space(1))) void*)(Bb + (size_t)r * K + (k0) + gch * 8), \
                (__attribute__((address_space(3))) void*)(&Bs[buf][w * 16 + p * 8][0]),   \
                16, 0, 0);                                                                \
        }                                                                                 \
    }

    ISSUE_LOADS64(0, 0)
    for (int ki = 0; ki < NIT; ++ki) {
        int cur = ki & 1;
        __syncthreads();
        if (ki + 1 < NIT) ISSUE_LOADS64(cur ^ 1, (ki + 1) * 64)
#pragma unroll
        for (int h = 0; h < 2; ++h) {
            bf16x8 af[2], bfr[2];
#pragma unroll
            for (int i = 0; i < 2; ++i)
                af[i] = *(const bf16x8*)&As[cur][wr + i * 16 + idx][(((q + 4 * h) ^ (idx & 7)) * 8)];
#pragma unroll
            for (int j = 0; j < 2; ++j)
                bfr[j] = *(const bf16x8*)&Bs[cur][wc + j * 16 + idx][(((q + 4 * h) ^ (idx & 7)) * 8)];
#pragma unroll
            for (int i = 0; i < 2; ++i)
#pragma unroll
                for (int j = 0; j < 2; ++j)
                    acc[i][j] = __builtin_amdgcn_mfma_f32_16x16x32_bf16(af[i], bfr[j], acc[i][j], 0, 0, 0);
        }
    }
#undef ISSUE_LOADS64

    // fp32 output Y[b][m][n]
#pragma unroll
    for (int i = 0; i < 2; ++i) {
        int m0 = mt * 64 + wr + i * 16 + q * 4;
        float b0 = bias[m0], b1 = bias[m0 + 1], b2 = bias[m0 + 2], b3 = bias[m0 + 3];
#pragma unroll
        for (int j = 0; j < 2; ++j) {
            int ng = nt * 64 + wc + j * 16 + idx;
            int bb = ng >> 10, nn = ng & 1023;
            f32x4 v = acc[i][j];
            float* p = Y + ((size_t)bb * M + m0) * NP + nn;
            p[0]      = v.x + b0;
            p[NP]     = v.y + b1;
            p[2 * NP] = v.z + b2;
            p[3 * NP] = v.w + b3;
        }
    }
}

extern "C" void kernel_launch(void* const* d_in, const int* in_sizes, int n_in,
                              void* d_out, int out_size, void* d_ws, size_t ws_size,
                              hipStream_t stream) {
    const float* x      = (const float*)d_in[0];
    const float* fc1_w  = (const float*)d_in[1];
    const float* fc1_b  = (const float*)d_in[2];
    const float* fc2_w  = (const float*)d_in[3];
    const float* fc2_b  = (const float*)d_in[4];
    const float* qkv_w  = (const float*)d_in[5];
    const float* qkv_b  = (const float*)d_in[6];
    const float* proj_w = (const float*)d_in[7];
    const float* proj_b = (const float*)d_in[8];
    const float* ffn1_w = (const float*)d_in[9];
    const float* ffn1_b = (const float*)d_in[10];
    const float* ffn2_w = (const float*)d_in[11];
    const float* ffn2_b = (const float*)d_in[12];
    float* out = (float*)d_out;

    // layout: [w1b 512K][w2b 512K][ygt 8M][ht 32M]; pre-FFN buffers overlap ht (dead by FFN1)
    u16* w1b = (u16*)d_ws;
    u16* w2b = w1b + 262144;
    u16* ygt = w2b + 262144;                         // [b*1024][256] bf16
    u16* ht  = ygt + (size_t)BB * NP * CC;           // [b*1024][1024] bf16
    float* s_mean = (float*)ht;                      // 16 KB
    u16* Qt = (u16*)(s_mean + BB * CC);              // 1 MB
    u16* Kt = Qt + (size_t)BB * NP * 32;             // 1 MB
    u16* Vb = Kt + (size_t)BB * NP * 32;             // 1 MB

    se_mean_conv_kernel<<<BB * CC + 512, 256, 0, stream>>>(x, s_mean, ffn1_w, w1b, ffn2_w, w2b);
    scale_transpose_qkv_kernel<<<dim3(16, 4, BB), 256, 0, stream>>>(
        x, s_mean, fc1_w, fc1_b, fc2_w, fc2_b, qkv_w, qkv_b, ygt, Qt, Kt, Vb);
    attn_mfma_kernel<<<BB * 64, 256, 0, stream>>>(Qt, Kt, Vb, proj_w, proj_b, ygt);

    // FFN1: ht[nflat][1024] bf16 (ReLU) = ffn1_w(1024x256) @ ygt
    mfma_gemm_kernel<256><<<dim3(8, 128), 256, 0, stream>>>(
        w1b, ygt, ffn1_b, ht, 1024);
    // FFN2: out[b][256][1024] fp32 = ffn2_w(256x1024) @ ht  (64x64 tiles, ~5 blocks/CU)
    mfma_gemm_64_kernel<1024><<<dim3(4, 256), 256, 0, stream>>>(
        w2b, ht, ffn2_b, out, 256);
}

// Round 10
// 173.203 us; speedup vs baseline: 1.1639x; 1.0501x over previous
//
#include <hip/hip_runtime.h>
#include <cstdint>
#include <cstddef>

#define BB 16
#define CC 256
#define NP 1024   // H*W

typedef __attribute__((ext_vector_type(8))) short bf16x8;
typedef __attribute__((ext_vector_type(4))) float f32x4;
typedef unsigned short u16;

__device__ __forceinline__ u16 f2bf(float f) {
    union { float f; uint32_t u; } v; v.f = f;
    uint32_t u = v.u;
    return (u16)((u + 0x7FFFu + ((u >> 16) & 1u)) >> 16);   // RNE
}

// ---------------- SE mean (blocks 0..4095) + weight convert (blocks 4096..4607) ----------------
__global__ __launch_bounds__(256)
void se_mean_conv_kernel(const float* __restrict__ x, float* __restrict__ s_mean,
                         const float* __restrict__ w1, u16* __restrict__ d1,
                         const float* __restrict__ w2, u16* __restrict__ d2) {
    int blk = blockIdx.x;
    int t = threadIdx.x;
    if (blk < BB * CC) {
        const float* p = x + (size_t)blk * NP;
        float4 v = *(const float4*)(p + t * 4);
        float s = (v.x + v.y) + (v.z + v.w);
#pragma unroll
        for (int off = 32; off; off >>= 1) s += __shfl_down(s, off, 64);
        __shared__ float red[4];
        if ((t & 63) == 0) red[t >> 6] = s;
        __syncthreads();
        if (t == 0) s_mean[blk] = (red[0] + red[1] + red[2] + red[3]) * (1.0f / NP);
    } else {
        int blk2 = blk - BB * CC;
        const float* src = (blk2 < 256) ? w1 : w2;
        u16* dst = (blk2 < 256) ? d1 : d2;
        int i = ((blk2 & 255) * 256 + t) * 4;
        float4 v = *(const float4*)(src + i);
        ushort4 o;
        o.x = f2bf(v.x); o.y = f2bf(v.y); o.z = f2bf(v.z); o.w = f2bf(v.w);
        *(ushort4*)(dst + i) = o;
    }
}

// ---- scale + transpose + per-block SE-mlp (+ fused qkv on ct==0 blocks) ----
__global__ __launch_bounds__(256)
void scale_transpose_qkv_kernel(const float* __restrict__ x, const float* __restrict__ s_mean,
                                const float* __restrict__ fc1_w, const float* __restrict__ fc1_b,
                                const float* __restrict__ fc2_w, const float* __restrict__ fc2_b,
                                const float* __restrict__ qW, const float* __restrict__ qB,
                                u16* __restrict__ ygt, u16* __restrict__ Qt,
                                u16* __restrict__ Kt, u16* __restrict__ Vb) {
    // grid: (16 nt, 4 ct, BB)
    int nt = blockIdx.x, ct = blockIdx.y, b = blockIdx.z;
    __shared__ float tile[64][65];
    __shared__ float ws[64 * 32];
    __shared__ float bs[64];
    __shared__ float vtile[32][64];
    __shared__ float smean_s[CC];
    __shared__ float h1[64];
    __shared__ float sig_l[64];
    int t = threadIdx.x;
    const float* Xb = x + ((size_t)b * CC + ct * 64) * NP + nt * 64;
    smean_s[t] = s_mean[b * CC + t];
    if (ct == 0) {
        for (int e = t; e < 2048; e += 256) ws[e] = qW[e];
        if (t < 64) bs[t] = qB[t];
    }
#pragma unroll
    for (int p = 0; p < 4; ++p) {
        int e = t + p * 256;
        int c = e >> 4, n4 = (e & 15) * 4;
        float4 v = *(const float4*)&Xb[(size_t)c * NP + n4];
        tile[c][n4] = v.x; tile[c][n4 + 1] = v.y; tile[c][n4 + 2] = v.z; tile[c][n4 + 3] = v.w;
    }
    __syncthreads();
    if (t < 64) {
        float a = fc1_b[t];
#pragma unroll 4
        for (int c = 0; c < CC; ++c) a += fc1_w[t * CC + c] * smean_s[c];
        h1[t] = fmaxf(a, 0.f);
    }
    __syncthreads();
    if (t < 64) {
        int c = ct * 64 + t;
        float a = fc2_b[c];
#pragma unroll 8
        for (int j = 0; j < 64; ++j) a += fc2_w[c * 64 + j] * h1[j];
        sig_l[t] = 1.f / (1.f + __expf(-a));
    }
    __syncthreads();
    u16* Yb = ygt + ((size_t)b * NP + nt * 64) * CC + ct * 64;
#pragma unroll
    for (int p = 0; p < 4; ++p) {
        int e = t + p * 256;
        int n = e >> 4, c4 = (e & 15) * 4;
        if (ct * 64 + c4 >= 32) {
            ushort4 o;
            o.x = f2bf(tile[c4][n] * sig_l[c4]);
            o.y = f2bf(tile[c4 + 1][n] * sig_l[c4 + 1]);
            o.z = f2bf(tile[c4 + 2][n] * sig_l[c4 + 2]);
            o.w = f2bf(tile[c4 + 3][n] * sig_l[c4 + 3]);
            *(ushort4*)&Yb[(size_t)n * CC + c4] = o;
        }
    }
    if (ct == 0) {
        int nn = t & 63, g = t >> 6;
        int n = nt * 64 + nn;
        float xs[32];
#pragma unroll
        for (int c = 0; c < 32; ++c) xs[c] = tile[c][nn] * sig_l[c];
        float acc[16];
#pragma unroll
        for (int oc = 0; oc < 16; ++oc) {
            int o = g * 16 + oc;
            float a = bs[o];
#pragma unroll
            for (int c = 0; c < 32; ++c) a += ws[o * 32 + c] * xs[c];
            acc[oc] = a;
        }
        if (g == 0) {
            u16* qr = Qt + ((size_t)b * NP + n) * 32;
            ushort4 z4; z4.x = 0; z4.y = 0; z4.z = 0; z4.w = 0;
#pragma unroll
            for (int j = 0; j < 16; j += 4) {
                ushort4 o4;
                o4.x = f2bf(acc[j] * 0.25f);     o4.y = f2bf(acc[j + 1] * 0.25f);
                o4.z = f2bf(acc[j + 2] * 0.25f); o4.w = f2bf(acc[j + 3] * 0.25f);
                *(ushort4*)&qr[j] = o4;
            }
            *(ushort4*)&qr[16] = z4; *(ushort4*)&qr[20] = z4;
            *(ushort4*)&qr[24] = z4; *(ushort4*)&qr[28] = z4;
        } else if (g == 1) {
            u16* kr = Kt + ((size_t)b * NP + n) * 32;
            ushort4 z4; z4.x = 0; z4.y = 0; z4.z = 0; z4.w = 0;
#pragma unroll
            for (int j = 0; j < 16; j += 4) {
                ushort4 k4;
                k4.x = f2bf(acc[j]);     k4.y = f2bf(acc[j + 1]);
                k4.z = f2bf(acc[j + 2]); k4.w = f2bf(acc[j + 3]);
                *(ushort4*)&kr[j] = k4;
            }
            *(ushort4*)&kr[16] = z4; *(ushort4*)&kr[20] = z4;
            *(ushort4*)&kr[24] = z4; *(ushort4*)&kr[28] = z4;
        } else {
#pragma unroll
            for (int oc = 0; oc < 16; ++oc) vtile[(g - 2) * 16 + oc][nn] = acc[oc];
        }
        __syncthreads();
        for (int e = t; e < 2048; e += 256) {
            int c = e >> 6, nn2 = e & 63;
            Vb[(size_t)b * 32 * NP + (size_t)c * NP + nt * 64 + nn2] = f2bf(vtile[c][nn2]);
        }
    }
}

// ---------------- MFMA flash attention + fused proj ----------------
__global__ __launch_bounds__(256)
void attn_mfma_kernel(const u16* __restrict__ Qt, const u16* __restrict__ Kt,
                      const u16* __restrict__ Vb,
                      const float* __restrict__ proj_w, const float* __restrict__ proj_b,
                      u16* __restrict__ ygt) {
    int b = blockIdx.x >> 6;
    int n0 = (blockIdx.x & 63) * 16;
    __shared__ __align__(16) u16 P_lds[4][16][40];
    __shared__ float al_lds[4][16];
    __shared__ float sm_lds[4][16];
    __shared__ float sl_lds[4][16];
    __shared__ float O_lds[4][16][33];
    __shared__ float pw_s[32][32];
    __shared__ float pb_s[32];
    int t = threadIdx.x;
    int w = t >> 6, lane = t & 63;
    int q = lane >> 4, idx = lane & 15;

    for (int e = t; e < 1024; e += 256) pw_s[e >> 5][e & 31] = proj_w[e];
    if (t < 32) pb_s[t] = proj_b[t];
    __syncthreads();

    const u16* Qb = Qt + (size_t)b * NP * 32;
    const u16* Kb = Kt + (size_t)b * NP * 32;
    const u16* Vp = Vb + (size_t)b * 32 * NP;

    int nrow = n0 + idx;
    bf16x8 aq = *(const bf16x8*)&Qb[(size_t)nrow * 32 + q * 8];

    f32x4 O0 = {0.f, 0.f, 0.f, 0.f}, O1 = {0.f, 0.f, 0.f, 0.f};
    float m_run[4] = {-1e30f, -1e30f, -1e30f, -1e30f};
    float l_run[4] = {0.f, 0.f, 0.f, 0.f};

    int mbase = w * 256;
    for (int m0 = mbase; m0 < mbase + 256; m0 += 32) {
        bf16x8 bk0 = *(const bf16x8*)&Kb[(size_t)(m0 + idx) * 32 + q * 8];
        bf16x8 bk1 = *(const bf16x8*)&Kb[(size_t)(m0 + 16 + idx) * 32 + q * 8];
        bf16x8 va0 = *(const bf16x8*)&Vp[(size_t)idx * NP + m0 + q * 8];
        bf16x8 va1 = *(const bf16x8*)&Vp[(size_t)(16 + idx) * NP + m0 + q * 8];
        f32x4 z = {0.f, 0.f, 0.f, 0.f};
        f32x4 S0 = __builtin_amdgcn_mfma_f32_16x16x32_bf16(aq, bk0, z, 0, 0, 0);
        f32x4 S1 = __builtin_amdgcn_mfma_f32_16x16x32_bf16(aq, bk1, z, 0, 0, 0);
        float mx[4], p0[4], p1[4], alpha[4];
#pragma unroll
        for (int r = 0; r < 4; ++r) mx[r] = fmaxf(S0[r], S1[r]);
#pragma unroll
        for (int off = 1; off < 16; off <<= 1)
#pragma unroll
            for (int r = 0; r < 4; ++r) mx[r] = fmaxf(mx[r], __shfl_xor(mx[r], off, 64));
#pragma unroll
        for (int r = 0; r < 4; ++r) {
            float nm = fmaxf(m_run[r], mx[r]);
            alpha[r] = __expf(m_run[r] - nm);
            m_run[r] = nm;
            p0[r] = __expf(S0[r] - nm);
            p1[r] = __expf(S1[r] - nm);
        }
#pragma unroll
        for (int r = 0; r < 4; ++r) {
            float s = p0[r] + p1[r];
#pragma unroll
            for (int off = 1; off < 16; off <<= 1) s += __shfl_xor(s, off, 64);
            l_run[r] = l_run[r] * alpha[r] + s;
        }
#pragma unroll
        for (int r = 0; r < 4; ++r) {
            P_lds[w][q * 4 + r][idx]      = f2bf(p0[r]);
            P_lds[w][q * 4 + r][idx + 16] = f2bf(p1[r]);
        }
        if (idx == 0) {
#pragma unroll
            for (int r = 0; r < 4; ++r) al_lds[w][q * 4 + r] = alpha[r];
        }
        float an = al_lds[w][idx];
#pragma unroll
        for (int r = 0; r < 4; ++r) { O0[r] *= an; O1[r] *= an; }
        bf16x8 pf = *(const bf16x8*)&P_lds[w][idx][q * 8];
        O0 = __builtin_amdgcn_mfma_f32_16x16x32_bf16(va0, pf, O0, 0, 0, 0);
        O1 = __builtin_amdgcn_mfma_f32_16x16x32_bf16(va1, pf, O1, 0, 0, 0);
    }
    if (idx == 0) {
#pragma unroll
        for (int r = 0; r < 4; ++r) {
            sm_lds[w][q * 4 + r] = m_run[r];
            sl_lds[w][q * 4 + r] = l_run[r];
        }
    }
#pragma unroll
    for (int r = 0; r < 4; ++r) {
        O_lds[w][idx][q * 4 + r]      = O0[r];
        O_lds[w][idx][q * 4 + r + 16] = O1[r];
    }
    __syncthreads();
    if (w == 0) {
        float m0_ = sm_lds[0][idx], m1 = sm_lds[1][idx], m2 = sm_lds[2][idx], m3 = sm_lds[3][idx];
        float gm = fmaxf(fmaxf(m0_, m1), fmaxf(m2, m3));
        float e0 = __expf(m0_ - gm), e1 = __expf(m1 - gm);
        float e2 = __expf(m2 - gm), e3 = __expf(m3 - gm);
        float linv = 1.f / (sl_lds[0][idx] * e0 + sl_lds[1][idx] * e1 +
                            sl_lds[2][idx] * e2 + sl_lds[3][idx] * e3);
#pragma unroll
        for (int r = 0; r < 4; ++r) {
            int c0 = q * 4 + r;
            O_lds[0][idx][c0] = (O_lds[0][idx][c0] * e0 + O_lds[1][idx][c0] * e1 +
                                 O_lds[2][idx][c0] * e2 + O_lds[3][idx][c0] * e3) * linv;
            int c1 = c0 + 16;
            O_lds[0][idx][c1] = (O_lds[0][idx][c1] * e0 + O_lds[1][idx][c1] * e1 +
                                 O_lds[2][idx][c1] * e2 + O_lds[3][idx][c1] * e3) * linv;
        }
        float o0[4], o1[4];
#pragma unroll
        for (int r = 0; r < 4; ++r) { o0[r] = pb_s[q * 4 + r]; o1[r] = pb_s[q * 4 + r + 16]; }
#pragma unroll
        for (int c = 0; c < 32; ++c) {
            float xv = O_lds[0][idx][c];
#pragma unroll
            for (int r = 0; r < 4; ++r) {
                o0[r] += pw_s[q * 4 + r][c] * xv;
                o1[r] += pw_s[q * 4 + r + 16][c] * xv;
            }
        }
        u16* yrow = ygt + ((size_t)b * NP + n0 + idx) * CC;
        ushort4 w0, w1;
        w0.x = f2bf(o0[0]); w0.y = f2bf(o0[1]); w0.z = f2bf(o0[2]); w0.w = f2bf(o0[3]);
        w1.x = f2bf(o1[0]); w1.y = f2bf(o1[1]); w1.z = f2bf(o1[2]); w1.w = f2bf(o1[3]);
        *(ushort4*)&yrow[q * 4] = w0;
        *(ushort4*)&yrow[q * 4 + 16] = w1;
    }
}

// ---------------- FFN1: 128x128 tile, BK=64, dbuf, LDS-bounced epilogue ----------------
// 1-D grid 1024, XCD-aware decode: all 8 mt-sharers of a B-tile (same nt) get the
// same id%8 -> same XCD -> B-tile fetched into one L2 instead of eight.
template <int K>
__global__ __launch_bounds__(256)
void mfma_gemm_kernel(const u16* __restrict__ A, const u16* __restrict__ Bt,
                      const float* __restrict__ bias, u16* __restrict__ Y, int M) {
    __shared__ __align__(16) u16 As[2][128][64];
    __shared__ __align__(16) u16 Bs[2][128][64];
    constexpr int NIT = K / 64;
    int id = blockIdx.x;
    int xcd = id & 7, qq = id >> 3;
    int mt = qq >> 4;                    // 0..7
    int nt = ((qq & 15) << 3) | xcd;     // 0..127, nt%8 == id%8
    const u16* Ab = A + (size_t)mt * 128 * K;
    const u16* Bb = Bt + (size_t)nt * 128 * K;
    int t = threadIdx.x;
    int w = t >> 6, lane = t & 63;
    int q = lane >> 4, idx = lane & 15;
    int wr = (w >> 1) * 64, wc = (w & 1) * 64;
    int srow = lane >> 3;
    int gch = (lane & 7) ^ srow;

    f32x4 acc[4][4];
#pragma unroll
    for (int i = 0; i < 4; ++i)
#pragma unroll
        for (int j = 0; j < 4; ++j) { f32x4 z = {0.f, 0.f, 0.f, 0.f}; acc[i][j] = z; }

#define ISSUE_LOADS(buf, k0)                                                              \
    {                                                                                     \
        _Pragma("unroll")                                                                 \
        for (int p = 0; p < 4; ++p) {                                                     \
            int r = w * 32 + p * 8 + srow;                                                \
            __builtin_amdgcn_global_load_lds(                                             \
                (const __attribute__((address_space(1))) void*)(Ab + (size_t)r * K + (k0) + gch * 8), \
                (__attribute__((address_space(3))) void*)(&As[buf][w * 32 + p * 8][0]),   \
                16, 0, 0);                                                                \
        }                                                                                 \
        _Pragma("unroll")                                                                 \
        for (int p = 0; p < 4; ++p) {                                                     \
            int r = w * 32 + p * 8 + srow;                                                \
            __builtin_amdgcn_global_load_lds(                                             \
                (const __attribute__((address_space(1))) void*)(Bb + (size_t)r * K + (k0) + gch * 8), \
                (__attribute__((address_space(3))) void*)(&Bs[buf][w * 32 + p * 8][0]),   \
                16, 0, 0);                                                                \
        }                                                                                 \
    }

    ISSUE_LOADS(0, 0)
    for (int ki = 0; ki < NIT; ++ki) {
        int cur = ki & 1;
        __syncthreads();
        if (ki + 1 < NIT) ISSUE_LOADS(cur ^ 1, (ki + 1) * 64)
#pragma unroll
        for (int h = 0; h < 2; ++h) {
            bf16x8 af[4], bfr[4];
#pragma unroll
            for (int i = 0; i < 4; ++i)
                af[i] = *(const bf16x8*)&As[cur][wr + i * 16 + idx][(((q + 4 * h) ^ (idx & 7)) * 8)];
#pragma unroll
            for (int j = 0; j < 4; ++j)
                bfr[j] = *(const bf16x8*)&Bs[cur][wc + j * 16 + idx][(((q + 4 * h) ^ (idx & 7)) * 8)];
#pragma unroll
            for (int i = 0; i < 4; ++i)
#pragma unroll
                for (int j = 0; j < 4; ++j)
                    acc[i][j] = __builtin_amdgcn_mfma_f32_16x16x32_bf16(af[i], bfr[j], acc[i][j], 0, 0, 0);
        }
    }
#undef ISSUE_LOADS

    // epilogue: bias+ReLU -> LDS tile [128 n][16 chunks, XOR(n&7)-swizzled] -> coalesced stores
    __syncthreads();
    u16* tile = &As[0][0][0];
#pragma unroll
    for (int i = 0; i < 4; ++i) {
        int m0 = wr + i * 16 + q * 4;
        int gm = mt * 128 + m0;
        float b0 = bias[gm], b1 = bias[gm + 1], b2 = bias[gm + 2], b3 = bias[gm + 3];
        int c16 = m0 >> 3;
        int off = (q & 1) * 4;
#pragma unroll
        for (int j = 0; j < 4; ++j) {
            int nl = wc + j * 16 + idx;
            f32x4 v = acc[i][j];
            ushort4 o;
            o.x = f2bf(fmaxf(v.x + b0, 0.f)); o.y = f2bf(fmaxf(v.y + b1, 0.f));
            o.z = f2bf(fmaxf(v.z + b2, 0.f)); o.w = f2bf(fmaxf(v.w + b3, 0.f));
            int cs = c16 ^ (nl & 7);
            *(ushort4*)&tile[nl * 128 + cs * 8 + off] = o;
        }
    }
    __syncthreads();
#pragma unroll
    for (int p = 0; p < 8; ++p) {
        int flat = p * 256 + t;
        int n = flat >> 4, c = flat & 15;
        int cs = c ^ (n & 7);
        bf16x8 v = *(const bf16x8*)&tile[n * 128 + cs * 8];
        *(bf16x8*)&Y[((size_t)(nt * 128 + n)) * (size_t)M + mt * 128 + c * 8] = v;
    }
}

// ---------------- FFN2: 64x64 tile, BK=64, dbuf, fp32 out ----------------
// 1-D grid 1024, XCD-aware decode: the 4 mt-sharers of a B-tile share id%8 -> same XCD.
template <int K>
__global__ __launch_bounds__(256)
void mfma_gemm_64_kernel(const u16* __restrict__ A, const u16* __restrict__ Bt,
                         const float* __restrict__ bias, float* __restrict__ Y, int M) {
    __shared__ __align__(16) u16 As[2][64][64];
    __shared__ __align__(16) u16 Bs[2][64][64];
    constexpr int NIT = K / 64;
    int id = blockIdx.x;
    int xcd = id & 7, qq = id >> 3;
    int mt = qq >> 5;                    // 0..3
    int nt = ((qq & 31) << 3) | xcd;     // 0..255
    const u16* Ab = A + (size_t)mt * 64 * K;
    const u16* Bb = Bt + (size_t)nt * 64 * K;
    int t = threadIdx.x;
    int w = t >> 6, lane = t & 63;
    int q = lane >> 4, idx = lane & 15;
    int wr = (w >> 1) * 32, wc = (w & 1) * 32;
    int srow = lane >> 3;
    int gch = (lane & 7) ^ srow;

    f32x4 acc[2][2];
#pragma unroll
    for (int i = 0; i < 2; ++i)
#pragma unroll
        for (int j = 0; j < 2; ++j) { f32x4 z = {0.f, 0.f, 0.f, 0.f}; acc[i][j] = z; }

#define ISSUE_LOADS64(buf, k0)                                                            \
    {                                                                                     \
        _Pragma("unroll")                                                                 \
        for (int p = 0; p < 2; ++p) {                                                     \
            int r = w * 16 + p * 8 + srow;                                                \
            __builtin_amdgcn_global_load_lds(                                             \
                (const __attribute__((address_space(1))) void*)(Ab + (size_t)r * K + (k0) + gch * 8), \
                (__attribute__((address_space(3))) void*)(&As[buf][w * 16 + p * 8][0]),   \
                16, 0, 0);                                                                \
        }                                                                                 \
        _Pragma("unroll")                                                                 \
        for (int p = 0; p < 2; ++p) {                                                     \
            int r = w * 16 + p * 8 + srow;                                                \
            __builtin_amdgcn_global_load_lds(                                             \
                (const __attribute__((address_space(1))) void*)(Bb + (size_t)r * K + (k0) + gch * 8), \
                (__attribute__((address_space(3))) void*)(&Bs[buf][w * 16 + p * 8][0]),   \
                16, 0, 0);                                                                \
        }                                                                                 \
    }

    ISSUE_LOADS64(0, 0)
    for (int ki = 0; ki < NIT; ++ki) {
        int cur = ki & 1;
        __syncthreads();
        if (ki + 1 < NIT) ISSUE_LOADS64(cur ^ 1, (ki + 1) * 64)
#pragma unroll
        for (int h = 0; h < 2; ++h) {
            bf16x8 af[2], bfr[2];
#pragma unroll
            for (int i = 0; i < 2; ++i)
                af[i] = *(const bf16x8*)&As[cur][wr + i * 16 + idx][(((q + 4 * h) ^ (idx & 7)) * 8)];
#pragma unroll
            for (int j = 0; j < 2; ++j)
                bfr[j] = *(const bf16x8*)&Bs[cur][wc + j * 16 + idx][(((q + 4 * h) ^ (idx & 7)) * 8)];
#pragma unroll
            for (int i = 0; i < 2; ++i)
#pragma unroll
                for (int j = 0; j < 2; ++j)
                    acc[i][j] = __builtin_amdgcn_mfma_f32_16x16x32_bf16(af[i], bfr[j], acc[i][j], 0, 0, 0);
        }
    }
#undef ISSUE_LOADS64

    // fp32 output Y[b][m][n]
#pragma unroll
    for (int i = 0; i < 2; ++i) {
        int m0 = mt * 64 + wr + i * 16 + q * 4;
        float b0 = bias[m0], b1 = bias[m0 + 1], b2 = bias[m0 + 2], b3 = bias[m0 + 3];
#pragma unroll
        for (int j = 0; j < 2; ++j) {
            int ng = nt * 64 + wc + j * 16 + idx;
            int bb = ng >> 10, nn = ng & 1023;
            f32x4 v = acc[i][j];
            float* p = Y + ((size_t)bb * M + m0) * NP + nn;
            p[0]      = v.x + b0;
            p[NP]     = v.y + b1;
            p[2 * NP] = v.z + b2;
            p[3 * NP] = v.w + b3;
        }
    }
}

extern "C" void kernel_launch(void* const* d_in, const int* in_sizes, int n_in,
                              void* d_out, int out_size, void* d_ws, size_t ws_size,
                              hipStream_t stream) {
    const float* x      = (const float*)d_in[0];
    const float* fc1_w  = (const float*)d_in[1];
    const float* fc1_b  = (const float*)d_in[2];
    const float* fc2_w  = (const float*)d_in[3];
    const float* fc2_b  = (const float*)d_in[4];
    const float* qkv_w  = (const float*)d_in[5];
    const float* qkv_b  = (const float*)d_in[6];
    const float* proj_w = (const float*)d_in[7];
    const float* proj_b = (const float*)d_in[8];
    const float* ffn1_w = (const float*)d_in[9];
    const float* ffn1_b = (const float*)d_in[10];
    const float* ffn2_w = (const float*)d_in[11];
    const float* ffn2_b = (const float*)d_in[12];
    float* out = (float*)d_out;

    // layout: [w1b 512K][w2b 512K][ygt 8M][ht 32M]; pre-FFN buffers overlap ht (dead by FFN1)
    u16* w1b = (u16*)d_ws;
    u16* w2b = w1b + 262144;
    u16* ygt = w2b + 262144;                         // [b*1024][256] bf16
    u16* ht  = ygt + (size_t)BB * NP * CC;           // [b*1024][1024] bf16
    float* s_mean = (float*)ht;                      // 16 KB
    u16* Qt = (u16*)(s_mean + BB * CC);              // 1 MB
    u16* Kt = Qt + (size_t)BB * NP * 32;             // 1 MB
    u16* Vb = Kt + (size_t)BB * NP * 32;             // 1 MB

    se_mean_conv_kernel<<<BB * CC + 512, 256, 0, stream>>>(x, s_mean, ffn1_w, w1b, ffn2_w, w2b);
    scale_transpose_qkv_kernel<<<dim3(16, 4, BB), 256, 0, stream>>>(
        x, s_mean, fc1_w, fc1_b, fc2_w, fc2_b, qkv_w, qkv_b, ygt, Qt, Kt, Vb);
    attn_mfma_kernel<<<BB * 64, 256, 0, stream>>>(Qt, Kt, Vb, proj_w, proj_b, ygt);

    // FFN1: ht[nflat][1024] bf16 (ReLU) = ffn1_w(1024x256) @ ygt   (XCD-swizzled 1-D grid)
    mfma_gemm_kernel<256><<<1024, 256, 0, stream>>>(w1b, ygt, ffn1_b, ht, 1024);
    // FFN2: out[b][256][1024] fp32 = ffn2_w(256x1024) @ ht          (XCD-swizzled 1-D grid)
    mfma_gemm_64_kernel<1024><<<1024, 256, 0, stream>>>(w2b, ht, ffn2_b, out, 256);
}

// Round 11
// 172.843 us; speedup vs baseline: 1.1663x; 1.0021x over previous
//
#include <hip/hip_runtime.h>
#include <cstdint>
#include <cstddef>

#define BB 16
#define CC 256
#define NP 1024   // H*W

typedef __attribute__((ext_vector_type(8))) short bf16x8;
typedef __attribute__((ext_vector_type(4))) float f32x4;
typedef unsigned short u16;

__device__ __forceinline__ u16 f2bf(float f) {
    union { float f; uint32_t u; } v; v.f = f;
    uint32_t u = v.u;
    return (u16)((u + 0x7FFFu + ((u >> 16) & 1u)) >> 16);   // RNE
}

// ---------------- SE mean (blocks 0..4095) + weight convert (blocks 4096..4607) ----------------
__global__ __launch_bounds__(256)
void se_mean_conv_kernel(const float* __restrict__ x, float* __restrict__ s_mean,
                         const float* __restrict__ w1, u16* __restrict__ d1,
                         const float* __restrict__ w2, u16* __restrict__ d2) {
    int blk = blockIdx.x;
    int t = threadIdx.x;
    if (blk < BB * CC) {
        const float* p = x + (size_t)blk * NP;
        float4 v = *(const float4*)(p + t * 4);
        float s = (v.x + v.y) + (v.z + v.w);
#pragma unroll
        for (int off = 32; off; off >>= 1) s += __shfl_down(s, off, 64);
        __shared__ float red[4];
        if ((t & 63) == 0) red[t >> 6] = s;
        __syncthreads();
        if (t == 0) s_mean[blk] = (red[0] + red[1] + red[2] + red[3]) * (1.0f / NP);
    } else {
        int blk2 = blk - BB * CC;
        const float* src = (blk2 < 256) ? w1 : w2;
        u16* dst = (blk2 < 256) ? d1 : d2;
        int i = ((blk2 & 255) * 256 + t) * 4;
        float4 v = *(const float4*)(src + i);
        ushort4 o;
        o.x = f2bf(v.x); o.y = f2bf(v.y); o.z = f2bf(v.z); o.w = f2bf(v.w);
        *(ushort4*)(dst + i) = o;
    }
}

// ---- scale + transpose + per-block SE-mlp (+ fused qkv on ct==0 blocks) ----
__global__ __launch_bounds__(256)
void scale_transpose_qkv_kernel(const float* __restrict__ x, const float* __restrict__ s_mean,
                                const float* __restrict__ fc1_w, const float* __restrict__ fc1_b,
                                const float* __restrict__ fc2_w, const float* __restrict__ fc2_b,
                                const float* __restrict__ qW, const float* __restrict__ qB,
                                u16* __restrict__ ygt, u16* __restrict__ Qt,
                                u16* __restrict__ Kt, u16* __restrict__ Vb) {
    // grid: (16 nt, 4 ct, BB)
    int nt = blockIdx.x, ct = blockIdx.y, b = blockIdx.z;
    __shared__ float tile[64][65];
    __shared__ float ws[64 * 32];
    __shared__ float bs[64];
    __shared__ float vtile[32][64];
    __shared__ float smean_s[CC];
    __shared__ float h1[64];
    __shared__ float sig_l[64];
    int t = threadIdx.x;
    const float* Xb = x + ((size_t)b * CC + ct * 64) * NP + nt * 64;
    smean_s[t] = s_mean[b * CC + t];
    if (ct == 0) {
        for (int e = t; e < 2048; e += 256) ws[e] = qW[e];
        if (t < 64) bs[t] = qB[t];
    }
#pragma unroll
    for (int p = 0; p < 4; ++p) {
        int e = t + p * 256;
        int c = e >> 4, n4 = (e & 15) * 4;
        float4 v = *(const float4*)&Xb[(size_t)c * NP + n4];
        tile[c][n4] = v.x; tile[c][n4 + 1] = v.y; tile[c][n4 + 2] = v.z; tile[c][n4 + 3] = v.w;
    }
    __syncthreads();
    if (t < 64) {
        float a = fc1_b[t];
#pragma unroll 4
        for (int c = 0; c < CC; ++c) a += fc1_w[t * CC + c] * smean_s[c];
        h1[t] = fmaxf(a, 0.f);
    }
    __syncthreads();
    if (t < 64) {
        int c = ct * 64 + t;
        float a = fc2_b[c];
#pragma unroll 8
        for (int j = 0; j < 64; ++j) a += fc2_w[c * 64 + j] * h1[j];
        sig_l[t] = 1.f / (1.f + __expf(-a));
    }
    __syncthreads();
    u16* Yb = ygt + ((size_t)b * NP + nt * 64) * CC + ct * 64;
#pragma unroll
    for (int p = 0; p < 4; ++p) {
        int e = t + p * 256;
        int n = e >> 4, c4 = (e & 15) * 4;
        if (ct * 64 + c4 >= 32) {
            ushort4 o;
            o.x = f2bf(tile[c4][n] * sig_l[c4]);
            o.y = f2bf(tile[c4 + 1][n] * sig_l[c4 + 1]);
            o.z = f2bf(tile[c4 + 2][n] * sig_l[c4 + 2]);
            o.w = f2bf(tile[c4 + 3][n] * sig_l[c4 + 3]);
            *(ushort4*)&Yb[(size_t)n * CC + c4] = o;
        }
    }
    if (ct == 0) {
        int nn = t & 63, g = t >> 6;
        int n = nt * 64 + nn;
        float xs[32];
#pragma unroll
        for (int c = 0; c < 32; ++c) xs[c] = tile[c][nn] * sig_l[c];
        float acc[16];
#pragma unroll
        for (int oc = 0; oc < 16; ++oc) {
            int o = g * 16 + oc;
            float a = bs[o];
#pragma unroll
            for (int c = 0; c < 32; ++c) a += ws[o * 32 + c] * xs[c];
            acc[oc] = a;
        }
        if (g == 0) {
            u16* qr = Qt + ((size_t)b * NP + n) * 32;
            ushort4 z4; z4.x = 0; z4.y = 0; z4.z = 0; z4.w = 0;
#pragma unroll
            for (int j = 0; j < 16; j += 4) {
                ushort4 o4;
                o4.x = f2bf(acc[j] * 0.25f);     o4.y = f2bf(acc[j + 1] * 0.25f);
                o4.z = f2bf(acc[j + 2] * 0.25f); o4.w = f2bf(acc[j + 3] * 0.25f);
                *(ushort4*)&qr[j] = o4;
            }
            *(ushort4*)&qr[16] = z4; *(ushort4*)&qr[20] = z4;
            *(ushort4*)&qr[24] = z4; *(ushort4*)&qr[28] = z4;
        } else if (g == 1) {
            u16* kr = Kt + ((size_t)b * NP + n) * 32;
            ushort4 z4; z4.x = 0; z4.y = 0; z4.z = 0; z4.w = 0;
#pragma unroll
            for (int j = 0; j < 16; j += 4) {
                ushort4 k4;
                k4.x = f2bf(acc[j]);     k4.y = f2bf(acc[j + 1]);
                k4.z = f2bf(acc[j + 2]); k4.w = f2bf(acc[j + 3]);
                *(ushort4*)&kr[j] = k4;
            }
            *(ushort4*)&kr[16] = z4; *(ushort4*)&kr[20] = z4;
            *(ushort4*)&kr[24] = z4; *(ushort4*)&kr[28] = z4;
        } else {
#pragma unroll
            for (int oc = 0; oc < 16; ++oc) vtile[(g - 2) * 16 + oc][nn] = acc[oc];
        }
        __syncthreads();
        for (int e = t; e < 2048; e += 256) {
            int c = e >> 6, nn2 = e & 63;
            Vb[(size_t)b * 32 * NP + (size_t)c * NP + nt * 64 + nn2] = f2bf(vtile[c][nn2]);
        }
    }
}

// ---------------- MFMA flash attention + fused proj ----------------
// XCD-swizzled: id = qt*16 + b  ->  id%8 = b%8, so each batch's K/V lives in one L2.
__global__ __launch_bounds__(256)
void attn_mfma_kernel(const u16* __restrict__ Qt, const u16* __restrict__ Kt,
                      const u16* __restrict__ Vb,
                      const float* __restrict__ proj_w, const float* __restrict__ proj_b,
                      u16* __restrict__ ygt) {
    int b = blockIdx.x & 15;
    int n0 = (blockIdx.x >> 4) * 16;
    __shared__ __align__(16) u16 P_lds[4][16][40];
    __shared__ float al_lds[4][16];
    __shared__ float sm_lds[4][16];
    __shared__ float sl_lds[4][16];
    __shared__ float O_lds[4][16][33];
    __shared__ float pw_s[32][32];
    __shared__ float pb_s[32];
    int t = threadIdx.x;
    int w = t >> 6, lane = t & 63;
    int q = lane >> 4, idx = lane & 15;

    for (int e = t; e < 1024; e += 256) pw_s[e >> 5][e & 31] = proj_w[e];
    if (t < 32) pb_s[t] = proj_b[t];
    __syncthreads();

    const u16* Qb = Qt + (size_t)b * NP * 32;
    const u16* Kb = Kt + (size_t)b * NP * 32;
    const u16* Vp = Vb + (size_t)b * 32 * NP;

    int nrow = n0 + idx;
    bf16x8 aq = *(const bf16x8*)&Qb[(size_t)nrow * 32 + q * 8];

    f32x4 O0 = {0.f, 0.f, 0.f, 0.f}, O1 = {0.f, 0.f, 0.f, 0.f};
    float m_run[4] = {-1e30f, -1e30f, -1e30f, -1e30f};
    float l_run[4] = {0.f, 0.f, 0.f, 0.f};

    int mbase = w * 256;
    for (int m0 = mbase; m0 < mbase + 256; m0 += 32) {
        bf16x8 bk0 = *(const bf16x8*)&Kb[(size_t)(m0 + idx) * 32 + q * 8];
        bf16x8 bk1 = *(const bf16x8*)&Kb[(size_t)(m0 + 16 + idx) * 32 + q * 8];
        bf16x8 va0 = *(const bf16x8*)&Vp[(size_t)idx * NP + m0 + q * 8];
        bf16x8 va1 = *(const bf16x8*)&Vp[(size_t)(16 + idx) * NP + m0 + q * 8];
        f32x4 z = {0.f, 0.f, 0.f, 0.f};
        f32x4 S0 = __builtin_amdgcn_mfma_f32_16x16x32_bf16(aq, bk0, z, 0, 0, 0);
        f32x4 S1 = __builtin_amdgcn_mfma_f32_16x16x32_bf16(aq, bk1, z, 0, 0, 0);
        float mx[4], p0[4], p1[4], alpha[4];
#pragma unroll
        for (int r = 0; r < 4; ++r) mx[r] = fmaxf(S0[r], S1[r]);
#pragma unroll
        for (int off = 1; off < 16; off <<= 1)
#pragma unroll
            for (int r = 0; r < 4; ++r) mx[r] = fmaxf(mx[r], __shfl_xor(mx[r], off, 64));
#pragma unroll
        for (int r = 0; r < 4; ++r) {
            float nm = fmaxf(m_run[r], mx[r]);
            alpha[r] = __expf(m_run[r] - nm);
            m_run[r] = nm;
            p0[r] = __expf(S0[r] - nm);
            p1[r] = __expf(S1[r] - nm);
        }
#pragma unroll
        for (int r = 0; r < 4; ++r) {
            float s = p0[r] + p1[r];
#pragma unroll
            for (int off = 1; off < 16; off <<= 1) s += __shfl_xor(s, off, 64);
            l_run[r] = l_run[r] * alpha[r] + s;
        }
#pragma unroll
        for (int r = 0; r < 4; ++r) {
            P_lds[w][q * 4 + r][idx]      = f2bf(p0[r]);
            P_lds[w][q * 4 + r][idx + 16] = f2bf(p1[r]);
        }
        if (idx == 0) {
#pragma unroll
            for (int r = 0; r < 4; ++r) al_lds[w][q * 4 + r] = alpha[r];
        }
        float an = al_lds[w][idx];
#pragma unroll
        for (int r = 0; r < 4; ++r) { O0[r] *= an; O1[r] *= an; }
        bf16x8 pf = *(const bf16x8*)&P_lds[w][idx][q * 8];
        O0 = __builtin_amdgcn_mfma_f32_16x16x32_bf16(va0, pf, O0, 0, 0, 0);
        O1 = __builtin_amdgcn_mfma_f32_16x16x32_bf16(va1, pf, O1, 0, 0, 0);
    }
    if (idx == 0) {
#pragma unroll
        for (int r = 0; r < 4; ++r) {
            sm_lds[w][q * 4 + r] = m_run[r];
            sl_lds[w][q * 4 + r] = l_run[r];
        }
    }
#pragma unroll
    for (int r = 0; r < 4; ++r) {
        O_lds[w][idx][q * 4 + r]      = O0[r];
        O_lds[w][idx][q * 4 + r + 16] = O1[r];
    }
    __syncthreads();
    if (w == 0) {
        float m0_ = sm_lds[0][idx], m1 = sm_lds[1][idx], m2 = sm_lds[2][idx], m3 = sm_lds[3][idx];
        float gm = fmaxf(fmaxf(m0_, m1), fmaxf(m2, m3));
        float e0 = __expf(m0_ - gm), e1 = __expf(m1 - gm);
        float e2 = __expf(m2 - gm), e3 = __expf(m3 - gm);
        float linv = 1.f / (sl_lds[0][idx] * e0 + sl_lds[1][idx] * e1 +
                            sl_lds[2][idx] * e2 + sl_lds[3][idx] * e3);
#pragma unroll
        for (int r = 0; r < 4; ++r) {
            int c0 = q * 4 + r;
            O_lds[0][idx][c0] = (O_lds[0][idx][c0] * e0 + O_lds[1][idx][c0] * e1 +
                                 O_lds[2][idx][c0] * e2 + O_lds[3][idx][c0] * e3) * linv;
            int c1 = c0 + 16;
            O_lds[0][idx][c1] = (O_lds[0][idx][c1] * e0 + O_lds[1][idx][c1] * e1 +
                                 O_lds[2][idx][c1] * e2 + O_lds[3][idx][c1] * e3) * linv;
        }
        float o0[4], o1[4];
#pragma unroll
        for (int r = 0; r < 4; ++r) { o0[r] = pb_s[q * 4 + r]; o1[r] = pb_s[q * 4 + r + 16]; }
#pragma unroll
        for (int c = 0; c < 32; ++c) {
            float xv = O_lds[0][idx][c];
#pragma unroll
            for (int r = 0; r < 4; ++r) {
                o0[r] += pw_s[q * 4 + r][c] * xv;
                o1[r] += pw_s[q * 4 + r + 16][c] * xv;
            }
        }
        u16* yrow = ygt + ((size_t)b * NP + n0 + idx) * CC;
        ushort4 w0, w1;
        w0.x = f2bf(o0[0]); w0.y = f2bf(o0[1]); w0.z = f2bf(o0[2]); w0.w = f2bf(o0[3]);
        w1.x = f2bf(o1[0]); w1.y = f2bf(o1[1]); w1.z = f2bf(o1[2]); w1.w = f2bf(o1[3]);
        *(ushort4*)&yrow[q * 4] = w0;
        *(ushort4*)&yrow[q * 4 + 16] = w1;
    }
}

// ---------------- FFN1: 128x128 tile, BK=64, dbuf, LDS-bounced epilogue ----------------
// 1-D grid 1024, XCD-aware decode: all 8 mt-sharers of a B-tile (same nt) share id%8.
template <int K>
__global__ __launch_bounds__(256)
void mfma_gemm_kernel(const u16* __restrict__ A, const u16* __restrict__ Bt,
                      const float* __restrict__ bias, u16* __restrict__ Y, int M) {
    __shared__ __align__(16) u16 As[2][128][64];
    __shared__ __align__(16) u16 Bs[2][128][64];
    constexpr int NIT = K / 64;
    int id = blockIdx.x;
    int xcd = id & 7, qq = id >> 3;
    int mt = qq >> 4;                    // 0..7
    int nt = ((qq & 15) << 3) | xcd;     // 0..127, nt%8 == id%8
    const u16* Ab = A + (size_t)mt * 128 * K;
    const u16* Bb = Bt + (size_t)nt * 128 * K;
    int t = threadIdx.x;
    int w = t >> 6, lane = t & 63;
    int q = lane >> 4, idx = lane & 15;
    int wr = (w >> 1) * 64, wc = (w & 1) * 64;
    int srow = lane >> 3;
    int gch = (lane & 7) ^ srow;

    f32x4 acc[4][4];
#pragma unroll
    for (int i = 0; i < 4; ++i)
#pragma unroll
        for (int j = 0; j < 4; ++j) { f32x4 z = {0.f, 0.f, 0.f, 0.f}; acc[i][j] = z; }

#define ISSUE_LOADS(buf, k0)                                                              \
    {                                                                                     \
        _Pragma("unroll")                                                                 \
        for (int p = 0; p < 4; ++p) {                                                     \
            int r = w * 32 + p * 8 + srow;                                                \
            __builtin_amdgcn_global_load_lds(                                             \
                (const __attribute__((address_space(1))) void*)(Ab + (size_t)r * K + (k0) + gch * 8), \
                (__attribute__((address_space(3))) void*)(&As[buf][w * 32 + p * 8][0]),   \
                16, 0, 0);                                                                \
        }                                                                                 \
        _Pragma("unroll")                                                                 \
        for (int p = 0; p < 4; ++p) {                                                     \
            int r = w * 32 + p * 8 + srow;                                                \
            __builtin_amdgcn_global_load_lds(                                             \
                (const __attribute__((address_space(1))) void*)(Bb + (size_t)r * K + (k0) + gch * 8), \
                (__attribute__((address_space(3))) void*)(&Bs[buf][w * 32 + p * 8][0]),   \
                16, 0, 0);                                                                \
        }                                                                                 \
    }

    ISSUE_LOADS(0, 0)
    for (int ki = 0; ki < NIT; ++ki) {
        int cur = ki & 1;
        __syncthreads();
        if (ki + 1 < NIT) ISSUE_LOADS(cur ^ 1, (ki + 1) * 64)
#pragma unroll
        for (int h = 0; h < 2; ++h) {
            bf16x8 af[4], bfr[4];
#pragma unroll
            for (int i = 0; i < 4; ++i)
                af[i] = *(const bf16x8*)&As[cur][wr + i * 16 + idx][(((q + 4 * h) ^ (idx & 7)) * 8)];
#pragma unroll
            for (int j = 0; j < 4; ++j)
                bfr[j] = *(const bf16x8*)&Bs[cur][wc + j * 16 + idx][(((q + 4 * h) ^ (idx & 7)) * 8)];
#pragma unroll
            for (int i = 0; i < 4; ++i)
#pragma unroll
                for (int j = 0; j < 4; ++j)
                    acc[i][j] = __builtin_amdgcn_mfma_f32_16x16x32_bf16(af[i], bfr[j], acc[i][j], 0, 0, 0);
        }
    }
#undef ISSUE_LOADS

    // epilogue: bias+ReLU -> LDS tile [128 n][16 chunks, XOR(n&7)-swizzled] -> coalesced stores
    __syncthreads();
    u16* tile = &As[0][0][0];
#pragma unroll
    for (int i = 0; i < 4; ++i) {
        int m0 = wr + i * 16 + q * 4;
        int gm = mt * 128 + m0;
        float b0 = bias[gm], b1 = bias[gm + 1], b2 = bias[gm + 2], b3 = bias[gm + 3];
        int c16 = m0 >> 3;
        int off = (q & 1) * 4;
#pragma unroll
        for (int j = 0; j < 4; ++j) {
            int nl = wc + j * 16 + idx;
            f32x4 v = acc[i][j];
            ushort4 o;
            o.x = f2bf(fmaxf(v.x + b0, 0.f)); o.y = f2bf(fmaxf(v.y + b1, 0.f));
            o.z = f2bf(fmaxf(v.z + b2, 0.f)); o.w = f2bf(fmaxf(v.w + b3, 0.f));
            int cs = c16 ^ (nl & 7);
            *(ushort4*)&tile[nl * 128 + cs * 8 + off] = o;
        }
    }
    __syncthreads();
#pragma unroll
    for (int p = 0; p < 8; ++p) {
        int flat = p * 256 + t;
        int n = flat >> 4, c = flat & 15;
        int cs = c ^ (n & 7);
        bf16x8 v = *(const bf16x8*)&tile[n * 128 + cs * 8];
        *(bf16x8*)&Y[((size_t)(nt * 128 + n)) * (size_t)M + mt * 128 + c * 8] = v;
    }
}

// ---------------- FFN2: 64x64 tile, BK=64, dbuf, fp32 out ----------------
// Producer-aligned XCD decode: xcd = (nt>>1)%8 == FFN1 writer's XCD for these ht rows,
// so B reads hit the local L2; the 4 mt-sharers of each B-tile still share the XCD.
template <int K>
__global__ __launch_bounds__(256)
void mfma_gemm_64_kernel(const u16* __restrict__ A, const u16* __restrict__ Bt,
                         const float* __restrict__ bias, float* __restrict__ Y, int M) {
    __shared__ __align__(16) u16 As[2][64][64];
    __shared__ __align__(16) u16 Bs[2][64][64];
    constexpr int NIT = K / 64;
    int id = blockIdx.x;
    int xcd = id & 7, u = id >> 3;       // u: 0..127
    int mt = u >> 5;                     // 0..3
    int j  = (u >> 1) & 15;              // 0..15
    int p_ = u & 1;                      // 0..1
    int nt = (((j << 3) | xcd) << 1) | p_;   // 0..255, (nt>>1)%8 == xcd
    const u16* Ab = A + (size_t)mt * 64 * K;
    const u16* Bb = Bt + (size_t)nt * 64 * K;
    int t = threadIdx.x;
    int w = t >> 6, lane = t & 63;
    int q = lane >> 4, idx = lane & 15;
    int wr = (w >> 1) * 32, wc = (w & 1) * 32;
    int srow = lane >> 3;
    int gch = (lane & 7) ^ srow;

    f32x4 acc[2][2];
#pragma unroll
    for (int i = 0; i < 2; ++i)
#pragma unroll
        for (int jj = 0; jj < 2; ++jj) { f32x4 z = {0.f, 0.f, 0.f, 0.f}; acc[i][jj] = z; }

#define ISSUE_LOADS64(buf, k0)                                                            \
    {                                                                                     \
        _Pragma("unroll")                                                                 \
        for (int p = 0; p < 2; ++p) {                                                     \
            int r = w * 16 + p * 8 + srow;                                                \
            __builtin_amdgcn_global_load_lds(                                             \
                (const __attribute__((address_space(1))) void*)(Ab + (size_t)r * K + (k0) + gch * 8), \
                (__attribute__((address_space(3))) void*)(&As[buf][w * 16 + p * 8][0]),   \
                16, 0, 0);                                                                \
        }                                                                                 \
        _Pragma("unroll")                                                                 \
        for (int p = 0; p < 2; ++p) {                                                     \
            int r = w * 16 + p * 8 + srow;                                                \
            __builtin_amdgcn_global_load_lds(                                             \
                (const __attribute__((address_space(1))) void*)(Bb + (size_t)r * K + (k0) + gch * 8), \
                (__attribute__((address_space(3))) void*)(&Bs[buf][w * 16 + p * 8][0]),   \
                16, 0, 0);                                                                \
        }                                                                                 \
    }

    ISSUE_LOADS64(0, 0)
    for (int ki = 0; ki < NIT; ++ki) {
        int cur = ki & 1;
        __syncthreads();
        if (ki + 1 < NIT) ISSUE_LOADS64(cur ^ 1, (ki + 1) * 64)
#pragma unroll
        for (int h = 0; h < 2; ++h) {
            bf16x8 af[2], bfr[2];
#pragma unroll
            for (int i = 0; i < 2; ++i)
                af[i] = *(const bf16x8*)&As[cur][wr + i * 16 + idx][(((q + 4 * h) ^ (idx & 7)) * 8)];
#pragma unroll
            for (int jj = 0; jj < 2; ++jj)
                bfr[jj] = *(const bf16x8*)&Bs[cur][wc + jj * 16 + idx][(((q + 4 * h) ^ (idx & 7)) * 8)];
#pragma unroll
            for (int i = 0; i < 2; ++i)
#pragma unroll
                for (int jj = 0; jj < 2; ++jj)
                    acc[i][jj] = __builtin_amdgcn_mfma_f32_16x16x32_bf16(af[i], bfr[jj], acc[i][jj], 0, 0, 0);
        }
    }
#undef ISSUE_LOADS64

    // fp32 output Y[b][m][n]
#pragma unroll
    for (int i = 0; i < 2; ++i) {
        int m0 = mt * 64 + wr + i * 16 + q * 4;
        float b0 = bias[m0], b1 = bias[m0 + 1], b2 = bias[m0 + 2], b3 = bias[m0 + 3];
#pragma unroll
        for (int jj = 0; jj < 2; ++jj) {
            int ng = nt * 64 + wc + jj * 16 + idx;
            int bb = ng >> 10, nn = ng & 1023;
            f32x4 v = acc[i][jj];
            float* p = Y + ((size_t)bb * M + m0) * NP + nn;
            p[0]      = v.x + b0;
            p[NP]     = v.y + b1;
            p[2 * NP] = v.z + b2;
            p[3 * NP] = v.w + b3;
        }
    }
}

extern "C" void kernel_launch(void* const* d_in, const int* in_sizes, int n_in,
                              void* d_out, int out_size, void* d_ws, size_t ws_size,
                              hipStream_t stream) {
    const float* x      = (const float*)d_in[0];
    const float* fc1_w  = (const float*)d_in[1];
    const float* fc1_b  = (const float*)d_in[2];
    const float* fc2_w  = (const float*)d_in[3];
    const float* fc2_b  = (const float*)d_in[4];
    const float* qkv_w  = (const float*)d_in[5];
    const float* qkv_b  = (const float*)d_in[6];
    const float* proj_w = (const float*)d_in[7];
    const float* proj_b = (const float*)d_in[8];
    const float* ffn1_w = (const float*)d_in[9];
    const float* ffn1_b = (const float*)d_in[10];
    const float* ffn2_w = (const float*)d_in[11];
    const float* ffn2_b = (const float*)d_in[12];
    float* out = (float*)d_out;

    // layout: [w1b 512K][w2b 512K][ygt 8M][ht 32M]; pre-FFN buffers overlap ht (dead by FFN1)
    u16* w1b = (u16*)d_ws;
    u16* w2b = w1b + 262144;
    u16* ygt = w2b + 262144;                         // [b*1024][256] bf16
    u16* ht  = ygt + (size_t)BB * NP * CC;           // [b*1024][1024] bf16
    float* s_mean = (float*)ht;                      // 16 KB
    u16* Qt = (u16*)(s_mean + BB * CC);              // 1 MB
    u16* Kt = Qt + (size_t)BB * NP * 32;             // 1 MB
    u16* Vb = Kt + (size_t)BB * NP * 32;             // 1 MB

    se_mean_conv_kernel<<<BB * CC + 512, 256, 0, stream>>>(x, s_mean, ffn1_w, w1b, ffn2_w, w2b);
    scale_transpose_qkv_kernel<<<dim3(16, 4, BB), 256, 0, stream>>>(
        x, s_mean, fc1_w, fc1_b, fc2_w, fc2_b, qkv_w, qkv_b, ygt, Qt, Kt, Vb);
    attn_mfma_kernel<<<BB * 64, 256, 0, stream>>>(Qt, Kt, Vb, proj_w, proj_b, ygt);

    // FFN1: ht[nflat][1024] bf16 (ReLU) = ffn1_w(1024x256) @ ygt   (XCD-swizzled)
    mfma_gemm_kernel<256><<<1024, 256, 0, stream>>>(w1b, ygt, ffn1_b, ht, 1024);
    // FFN2: out[b][256][1024] fp32 = ffn2_w(256x1024) @ ht          (producer-aligned XCD)
    mfma_gemm_64_kernel<1024><<<1024, 256, 0, stream>>>(w2b, ht, ffn2_b, out, 256);
}